// Round 1
// baseline (1140.494 us; speedup 1.0000x reference)
//
#include <hip/hip_runtime.h>

// Linear RNN chunked scan on MI355X.
// x_{k+1} = x_k @ A + u_k @ Bm + b ;  Y_t = x_t @ W2^T + yb
// NY=64 NU=32 NH=512 NHRZ=2048 B=128.  T_CH=64 chunks of S_LEN=32 steps.
// Pass1: per-chunk remainder from zero state (parallel).
// Combine: s_{j+1} = s_j @ A^32 + r_j (serial over 64 chunks only).
// Pass2: rerun chunks from true starts, fuse Y projection (X never stored).
// All MFMA in f16 (eps 5e-4; error decays since spectral radius ~0.97), f32 accum.

#define S_LEN 32
#define T_CH  64

typedef _Float16 h8 __attribute__((ext_vector_type(8)));
typedef float    f4 __attribute__((ext_vector_type(4)));

__device__ __forceinline__ f4 MFMA16(h8 a, h8 b, f4 c) {
  return __builtin_amdgcn_mfma_f32_16x16x32_f16(a, b, c, 0, 0, 0);
}
// Swizzled LDS address for state tile [rows][512] f16, row stride 1024 B.
// XOR of (row&7)<<4 keeps 16B fragments intact, kills the stride-1024 bank conflict.
__device__ __forceinline__ int xoff(int row, int bc) {
  return row * 1024 + (bc ^ ((row & 7) << 4));
}
__device__ __forceinline__ unsigned short f2h_bits(float f) {
  _Float16 h = (_Float16)f;
  return __builtin_bit_cast(unsigned short, h);
}

// ---------------- prep: pack weights to f16 fragment-friendly layouts ----------------
// A_pk  [32 tn][64 kb][16 ln][8 j] = A[k=kb*8+j][n=tn*16+ln] = xu2x_w[n][k]   (512 KB)
// Bm_pk [32 tn][ 4 kb][16 ln][8 j] = Bm[k][n] = xu2x_w[n][512+k]              (32 KB)
// W2_pk [ 4 tn][64 kb][16 ln][8 j] = W2T[k][n] = x2y_w[n*512+k]               (64 KB)
// A_rm  [512 k][512 n] = xu2x_w[n][k]  (row-major, A-operand side of squaring)
__global__ __launch_bounds__(256) void k_prep(
    const float* __restrict__ xw, const float* __restrict__ yw,
    _Float16* __restrict__ A_pk, _Float16* __restrict__ Bm_pk,
    _Float16* __restrict__ W2_pk, _Float16* __restrict__ A_rm) {
  int tid = blockIdx.x * 256 + threadIdx.x;
  if (tid < 32768) {
    int g = tid; int ln = g & 15, kb = (g >> 4) & 63, tn = g >> 10;
    const float* s = xw + (tn * 16 + ln) * 544 + kb * 8;
    _Float16* d = A_pk + (size_t)g * 8;
#pragma unroll
    for (int j = 0; j < 8; j++) d[j] = (_Float16)s[j];
  } else if (tid < 34816) {
    int g = tid - 32768; int ln = g & 15, kb = (g >> 4) & 3, tn = g >> 6;
    const float* s = xw + (tn * 16 + ln) * 544 + 512 + kb * 8;
    _Float16* d = Bm_pk + (size_t)g * 8;
#pragma unroll
    for (int j = 0; j < 8; j++) d[j] = (_Float16)s[j];
  } else if (tid < 38912) {
    int g = tid - 34816; int ln = g & 15, kb = (g >> 4) & 63, tn = g >> 10;
    const float* s = yw + (tn * 16 + ln) * 512 + kb * 8;
    _Float16* d = W2_pk + (size_t)g * 8;
#pragma unroll
    for (int j = 0; j < 8; j++) d[j] = (_Float16)s[j];
  } else if (tid < 71680) {
    int g = tid - 38912; int k = g >> 6, n8 = (g & 63) * 8;
#pragma unroll
    for (int j = 0; j < 8; j++) A_rm[(size_t)k * 512 + n8 + j] = (_Float16)xw[(size_t)(n8 + j) * 544 + k];
  }
}

// ---------------- x0 = y0 @ y2x_w^T + y2x_b  (f32, tiny) ----------------
__global__ __launch_bounds__(256) void k_x0(
    const float* __restrict__ y0, const float* __restrict__ w,
    const float* __restrict__ b, float* __restrict__ x0) {
  int tid = blockIdx.x * 256 + threadIdx.x;  // 65536 = 128*512
  int bb = tid >> 9, h = tid & 511;
  float acc = b[h];
  const float* wr = w + h * 64;
  const float* yr = y0 + bb * 64;
#pragma unroll 8
  for (int i = 0; i < 64; i++) acc += yr[i] * wr[i];
  x0[(size_t)bb * 512 + h] = acc;
}

// ---------------- squaring GEMM: P = M @ M (for A^2..A^32) ----------------
// rm_in: M row-major f16 (A-operand), pk_in: M packed (B-operand).
// Writes both rm_out and pk_out so the chain can continue.
__global__ __launch_bounds__(256) void k_sq(
    const _Float16* __restrict__ rm_in, const _Float16* __restrict__ pk_in,
    _Float16* __restrict__ rm_out, _Float16* __restrict__ pk_out) {
  int w = threadIdx.x >> 6;
  int ln = threadIdx.x & 15, g = (threadIdx.x >> 4) & 3;
  int Mb = (blockIdx.x >> 3) * 64, Nb = (blockIdx.x & 7) * 64;
  int mrow = Mb + w * 16 + ln;
  f4 acc[4];
#pragma unroll
  for (int i = 0; i < 4; i++) { f4 z = {0.f, 0.f, 0.f, 0.f}; acc[i] = z; }
  for (int k0 = 0; k0 < 512; k0 += 32) {
    h8 af = *(const h8*)(rm_in + (size_t)mrow * 512 + k0 + g * 8);
#pragma unroll
    for (int i = 0; i < 4; i++) {
      int tn = (Nb >> 4) + i;
      h8 bf = *(const h8*)(pk_in + ((size_t)(tn * 64 + (k0 >> 3) + g) * 16 + ln) * 8);
      acc[i] = MFMA16(af, bf, acc[i]);
    }
  }
  int mr0 = Mb + w * 16 + g * 4;
#pragma unroll
  for (int i = 0; i < 4; i++) {
    int n = Nb + i * 16 + ln;
#pragma unroll
    for (int r = 0; r < 4; r++) rm_out[(size_t)(mr0 + r) * 512 + n] = (_Float16)acc[i][r];
    _Float16* pd = pk_out + (size_t)((n >> 4) * 64 + (mr0 >> 3)) * 128 + (n & 15) * 8 + (mr0 & 7);
#pragma unroll
    for (int r = 0; r < 4; r++) pd[r] = (_Float16)acc[i][r];
  }
}

// ---------------- pass 1: chunk remainders from zero state ----------------
// grid (4 rowblocks, 64 chunks), 512 thr. Z[j] <- state after 32 steps from 0.
__global__ __launch_bounds__(512) void k_pass1(
    const float* __restrict__ U, const _Float16* __restrict__ A_pk,
    const _Float16* __restrict__ Bm_pk, const float* __restrict__ xb,
    float* __restrict__ Z) {
  extern __shared__ char smem[];
  char* buf0 = smem;
  char* buf1 = smem + 32768;
  const int rb = blockIdx.x, j = blockIdx.y;
  const int row0 = rb * 32;
  const int tid = threadIdx.x;
  const int w = tid >> 6, ln = tid & 15, g = (tid >> 4) & 3;
  float bias[4];
  h8 bmf[4];
#pragma unroll
  for (int i = 0; i < 4; i++) {
    int tn = w * 4 + i;
    bias[i] = xb[tn * 16 + ln];
    bmf[i] = *(const h8*)(Bm_pk + ((size_t)(tn * 4 + g) * 16 + ln) * 8);
  }
  char* cur = buf0;
  char* nxt = buf1;
#pragma unroll 1
  for (int t = 0; t < S_LEN; t++) {
    f4 acc[2][4];
#pragma unroll
    for (int tm = 0; tm < 2; tm++)
#pragma unroll
      for (int i = 0; i < 4; i++) {
        f4 v = {bias[i], bias[i], bias[i], bias[i]};
        acc[tm][i] = v;
      }
    const int ku = j * S_LEN + t;
#pragma unroll
    for (int tm = 0; tm < 2; tm++) {
      const float* up = U + ((size_t)ku * 128 + row0 + tm * 16 + ln) * 32 + g * 8;
      const float4 ua = *(const float4*)up;
      const float4 ub = *(const float4*)(up + 4);
      h8 uf;
      uf[0] = (_Float16)ua.x; uf[1] = (_Float16)ua.y; uf[2] = (_Float16)ua.z; uf[3] = (_Float16)ua.w;
      uf[4] = (_Float16)ub.x; uf[5] = (_Float16)ub.y; uf[6] = (_Float16)ub.z; uf[7] = (_Float16)ub.w;
#pragma unroll
      for (int i = 0; i < 4; i++) acc[tm][i] = MFMA16(uf, bmf[i], acc[tm][i]);
    }
    if (t > 0) {
#pragma unroll 4
      for (int k0 = 0; k0 < 512; k0 += 32) {
        const int bc = 2 * k0 + 16 * g;
        h8 xa0 = *(const h8*)(cur + xoff(ln, bc));
        h8 xa1 = *(const h8*)(cur + xoff(16 + ln, bc));
#pragma unroll
        for (int i = 0; i < 4; i++) {
          int tn = w * 4 + i;
          h8 bf = *(const h8*)(A_pk + ((size_t)(tn * 64 + (k0 >> 3) + g) * 16 + ln) * 8);
          acc[0][i] = MFMA16(xa0, bf, acc[0][i]);
          acc[1][i] = MFMA16(xa1, bf, acc[1][i]);
        }
      }
    }
    if (t < S_LEN - 1) {
#pragma unroll
      for (int tm = 0; tm < 2; tm++)
#pragma unroll
        for (int i = 0; i < 4; i++) {
          const int n = (w * 4 + i) * 16 + ln;
#pragma unroll
          for (int r = 0; r < 4; r++) {
            const int mr = tm * 16 + g * 4 + r;
            *(unsigned short*)(nxt + xoff(mr, 2 * n)) = f2h_bits(acc[tm][i][r]);
          }
        }
      __syncthreads();
      char* tp = cur; cur = nxt; nxt = tp;
    } else {
#pragma unroll
      for (int tm = 0; tm < 2; tm++)
#pragma unroll
        for (int i = 0; i < 4; i++) {
          const int n = (w * 4 + i) * 16 + ln;
#pragma unroll
          for (int r = 0; r < 4; r++) {
            const int mr = tm * 16 + g * 4 + r;
            Z[((size_t)j * 128 + row0 + mr) * 512 + n] = acc[tm][i][r];
          }
        }
    }
  }
}

// ---------------- combine: s_{j+1} = s_j @ A^32 + r_j  (serial over 64) ----------------
// grid 8 (16 rows each). Z[j] is overwritten in place with s_{j+1}.
__global__ __launch_bounds__(512) void k_combine(
    const _Float16* __restrict__ AS_pk, const float* __restrict__ x0,
    float* __restrict__ Z) {
  extern __shared__ char smem[];
  char* buf0 = smem;
  char* buf1 = smem + 16384;
  const int row0 = blockIdx.x * 16;
  const int tid = threadIdx.x;
  const int w = tid >> 6, ln = tid & 15, g = (tid >> 4) & 3;
  {
    const int row = tid >> 5;
    const int c = (tid & 31) * 16;
    const float* s = x0 + (size_t)(row0 + row) * 512 + c;
#pragma unroll
    for (int q = 0; q < 2; q++) {
      h8 hv;
#pragma unroll
      for (int e = 0; e < 8; e++) hv[e] = (_Float16)s[q * 8 + e];
      *(h8*)(buf0 + xoff(row, 2 * (c + q * 8))) = hv;
    }
  }
  __syncthreads();
  char* cur = buf0;
  char* nxt = buf1;
#pragma unroll 1
  for (int j = 0; j < T_CH; j++) {
    f4 acc[4];
#pragma unroll
    for (int i = 0; i < 4; i++) {
      const int n = (w * 4 + i) * 16 + ln;
#pragma unroll
      for (int r = 0; r < 4; r++)
        acc[i][r] = Z[((size_t)j * 128 + row0 + g * 4 + r) * 512 + n];
    }
#pragma unroll 4
    for (int k0 = 0; k0 < 512; k0 += 32) {
      h8 xa = *(const h8*)(cur + xoff(ln, 2 * k0 + 16 * g));
#pragma unroll
      for (int i = 0; i < 4; i++) {
        int tn = w * 4 + i;
        h8 bf = *(const h8*)(AS_pk + ((size_t)(tn * 64 + (k0 >> 3) + g) * 16 + ln) * 8);
        acc[i] = MFMA16(xa, bf, acc[i]);
      }
    }
#pragma unroll
    for (int i = 0; i < 4; i++) {
      const int n = (w * 4 + i) * 16 + ln;
#pragma unroll
      for (int r = 0; r < 4; r++) {
        const int mr = g * 4 + r;
        *(unsigned short*)(nxt + xoff(mr, 2 * n)) = f2h_bits(acc[i][r]);
        Z[((size_t)j * 128 + row0 + mr) * 512 + n] = acc[i][r];
      }
    }
    __syncthreads();
    char* tp = cur; cur = nxt; nxt = tp;
  }
}

// ---------------- pass 2: rerun chunks from true starts, fused Y projection ----------------
// grid (4 rowblocks, 64 chunks). Chunk j emits Y[j*32 + t], t=0..31 (last chunk also t=32).
__global__ __launch_bounds__(512) void k_pass2(
    const float* __restrict__ U, const _Float16* __restrict__ A_pk,
    const _Float16* __restrict__ Bm_pk, const _Float16* __restrict__ W2_pk,
    const float* __restrict__ xb, const float* __restrict__ yb,
    const float* __restrict__ x0, const float* __restrict__ Z,
    float* __restrict__ Y) {
  extern __shared__ char smem[];
  char* buf0 = smem;
  char* buf1 = smem + 32768;
  char* w2l = smem + 65536;
  const int rb = blockIdx.x, j = blockIdx.y;
  const int row0 = rb * 32;
  const int tid = threadIdx.x;
  const int w = tid >> 6, ln = tid & 15, g = (tid >> 4) & 3;
  {
    const uint4* s = (const uint4*)W2_pk;
    uint4* d = (uint4*)w2l;
#pragma unroll
    for (int q = 0; q < 8; q++) d[tid + q * 512] = s[tid + q * 512];
  }
  {
    const float* start = (j == 0) ? x0 : (Z + (size_t)(j - 1) * 128 * 512);
    const int row = tid >> 4;
    const int c0 = (tid & 15) * 32;
    const float* s = start + (size_t)(row0 + row) * 512 + c0;
#pragma unroll
    for (int q = 0; q < 4; q++) {
      h8 hv;
#pragma unroll
      for (int e = 0; e < 8; e++) hv[e] = (_Float16)s[q * 8 + e];
      *(h8*)(buf0 + xoff(row, 2 * (c0 + q * 8))) = hv;
    }
  }
  __syncthreads();

  const int tmp_ = w >> 2, tnp = w & 3;
  const float ybv = yb[tnp * 16 + ln];
  auto proj = [&](const char* xs, int tg) {
    f4 p0 = {ybv, ybv, ybv, ybv};
    f4 p1 = {0.f, 0.f, 0.f, 0.f};
#pragma unroll 4
    for (int kk = 0; kk < 16; kk++) {
      const int k0 = kk * 32;
      h8 xa = *(const h8*)(xs + xoff(tmp_ * 16 + ln, 2 * k0 + 16 * g));
      h8 wf = *(const h8*)(w2l + ((size_t)(tnp * 64 + (k0 >> 3) + g) * 16 + ln) * 16);
      if (kk & 1) p1 = MFMA16(xa, wf, p1);
      else        p0 = MFMA16(xa, wf, p0);
    }
#pragma unroll
    for (int r = 0; r < 4; r++)
      Y[((size_t)tg * 128 + row0 + tmp_ * 16 + g * 4 + r) * 64 + tnp * 16 + ln] = p0[r] + p1[r];
  };

  proj(buf0, j * S_LEN);

  float bias[4];
  h8 bmf[4];
#pragma unroll
  for (int i = 0; i < 4; i++) {
    int tn = w * 4 + i;
    bias[i] = xb[tn * 16 + ln];
    bmf[i] = *(const h8*)(Bm_pk + ((size_t)(tn * 4 + g) * 16 + ln) * 8);
  }

  const int tend = (j == T_CH - 1) ? S_LEN : (S_LEN - 1);
  char* cur = buf0;
  char* nxt = buf1;
#pragma unroll 1
  for (int t = 1; t <= tend; t++) {
    f4 acc[2][4];
#pragma unroll
    for (int tm = 0; tm < 2; tm++)
#pragma unroll
      for (int i = 0; i < 4; i++) {
        f4 v = {bias[i], bias[i], bias[i], bias[i]};
        acc[tm][i] = v;
      }
    const int ku = j * S_LEN + t - 1;
#pragma unroll
    for (int tm = 0; tm < 2; tm++) {
      const float* up = U + ((size_t)ku * 128 + row0 + tm * 16 + ln) * 32 + g * 8;
      const float4 ua = *(const float4*)up;
      const float4 ub = *(const float4*)(up + 4);
      h8 uf;
      uf[0] = (_Float16)ua.x; uf[1] = (_Float16)ua.y; uf[2] = (_Float16)ua.z; uf[3] = (_Float16)ua.w;
      uf[4] = (_Float16)ub.x; uf[5] = (_Float16)ub.y; uf[6] = (_Float16)ub.z; uf[7] = (_Float16)ub.w;
#pragma unroll
      for (int i = 0; i < 4; i++) acc[tm][i] = MFMA16(uf, bmf[i], acc[tm][i]);
    }
#pragma unroll 4
    for (int k0 = 0; k0 < 512; k0 += 32) {
      const int bc = 2 * k0 + 16 * g;
      h8 xa0 = *(const h8*)(cur + xoff(ln, bc));
      h8 xa1 = *(const h8*)(cur + xoff(16 + ln, bc));
#pragma unroll
      for (int i = 0; i < 4; i++) {
        int tn = w * 4 + i;
        h8 bf = *(const h8*)(A_pk + ((size_t)(tn * 64 + (k0 >> 3) + g) * 16 + ln) * 8);
        acc[0][i] = MFMA16(xa0, bf, acc[0][i]);
        acc[1][i] = MFMA16(xa1, bf, acc[1][i]);
      }
    }
#pragma unroll
    for (int tm = 0; tm < 2; tm++)
#pragma unroll
      for (int i = 0; i < 4; i++) {
        const int n = (w * 4 + i) * 16 + ln;
#pragma unroll
        for (int r = 0; r < 4; r++) {
          const int mr = tm * 16 + g * 4 + r;
          *(unsigned short*)(nxt + xoff(mr, 2 * n)) = f2h_bits(acc[tm][i][r]);
        }
      }
    __syncthreads();
    proj(nxt, j * S_LEN + t);
    char* tp = cur; cur = nxt; nxt = tp;
  }
}

extern "C" void kernel_launch(void* const* d_in, const int* in_sizes, int n_in,
                              void* d_out, int out_size, void* d_ws, size_t ws_size,
                              hipStream_t stream) {
  const float* y0   = (const float*)d_in[0];
  const float* U    = (const float*)d_in[1];
  const float* y2xw = (const float*)d_in[2];
  const float* y2xb = (const float*)d_in[3];
  const float* xw   = (const float*)d_in[4];
  const float* xub  = (const float*)d_in[5];
  const float* x2yw = (const float*)d_in[6];
  const float* x2yb = (const float*)d_in[7];
  float* Y = (float*)d_out;
  char* ws = (char*)d_ws;

  _Float16* A_pk  = (_Float16*)(ws);
  _Float16* Bm_pk = (_Float16*)(ws + 0x80000);
  _Float16* W2_pk = (_Float16*)(ws + 0x88000);
  float*    x0    = (float*)   (ws + 0x98000);
  _Float16* rm_a  = (_Float16*)(ws + 0xD8000);
  _Float16* rm_b  = (_Float16*)(ws + 0x158000);
  _Float16* pk_a  = (_Float16*)(ws + 0x1D8000);
  _Float16* pk_b  = (_Float16*)(ws + 0x258000);
  float*    Z     = (float*)   (ws + 0x2D8000);  // 64*128*512*4 = 16 MB

  k_prep<<<280, 256, 0, stream>>>(xw, x2yw, A_pk, Bm_pk, W2_pk, rm_a);
  k_x0<<<256, 256, 0, stream>>>(y0, y2xw, y2xb, x0);
  // A^2, A^4, A^8, A^16, A^32 by repeated squaring
  k_sq<<<64, 256, 0, stream>>>(rm_a, A_pk, rm_b, pk_b);
  k_sq<<<64, 256, 0, stream>>>(rm_b, pk_b, rm_a, pk_a);
  k_sq<<<64, 256, 0, stream>>>(rm_a, pk_a, rm_b, pk_b);
  k_sq<<<64, 256, 0, stream>>>(rm_b, pk_b, rm_a, pk_a);
  k_sq<<<64, 256, 0, stream>>>(rm_a, pk_a, rm_b, pk_b);  // pk_b = packed A^32
  k_pass1<<<dim3(4, T_CH), 512, 65536, stream>>>(U, A_pk, Bm_pk, xub, Z);
  k_combine<<<8, 512, 32768, stream>>>(pk_b, x0, Z);
  k_pass2<<<dim3(4, T_CH), 512, 131072, stream>>>(U, A_pk, Bm_pk, W2_pk, xub, x2yb, x0, Z, Y);
}

// Round 2
// 815.776 us; speedup vs baseline: 1.3980x; 1.3980x over previous
//
#include <hip/hip_runtime.h>

// Linear RNN chunked scan on MI355X.
// x_{k+1} = x_k @ A + u_k @ Bm + b ;  Y_t = x_t @ W2^T + yb
// NY=64 NU=32 NH=512 NHRZ=2048 B=128.  T_CH=64 chunks of S_LEN=32 steps.
// Pass1: per-chunk remainder (chunk 0 starts from x0), parallel.
// Scan:  Kogge-Stone over chunks: Z[j] += Z[j-d] @ A^{32d}, d=1..32 (6 sweeps,
//        fully parallel — replaces the 500us serial combine of round 0).
// Pass2: rerun chunks from true starts, fuse Y projection (X never stored).
// All MFMA in f16 (error decays, spectral radius ~0.97), f32 accum. Z kept f16.

#define S_LEN 32
#define T_CH  64

typedef _Float16 h8 __attribute__((ext_vector_type(8)));
typedef float    f4 __attribute__((ext_vector_type(4)));

__device__ __forceinline__ f4 MFMA16(h8 a, h8 b, f4 c) {
  return __builtin_amdgcn_mfma_f32_16x16x32_f16(a, b, c, 0, 0, 0);
}
// Swizzled LDS address for state tile [rows][512] f16, row stride 1024 B.
__device__ __forceinline__ int xoff(int row, int bc) {
  return row * 1024 + (bc ^ ((row & 7) << 4));
}

// ---------------- prep: pack weights to f16 fragment-friendly layouts ----------------
__global__ __launch_bounds__(256) void k_prep(
    const float* __restrict__ xw, const float* __restrict__ yw,
    _Float16* __restrict__ A_pk, _Float16* __restrict__ Bm_pk,
    _Float16* __restrict__ W2_pk, _Float16* __restrict__ A_rm) {
  int tid = blockIdx.x * 256 + threadIdx.x;
  if (tid < 32768) {
    int g = tid; int ln = g & 15, kb = (g >> 4) & 63, tn = g >> 10;
    const float* s = xw + (tn * 16 + ln) * 544 + kb * 8;
    _Float16* d = A_pk + (size_t)g * 8;
#pragma unroll
    for (int j = 0; j < 8; j++) d[j] = (_Float16)s[j];
  } else if (tid < 34816) {
    int g = tid - 32768; int ln = g & 15, kb = (g >> 4) & 3, tn = g >> 6;
    const float* s = xw + (tn * 16 + ln) * 544 + 512 + kb * 8;
    _Float16* d = Bm_pk + (size_t)g * 8;
#pragma unroll
    for (int j = 0; j < 8; j++) d[j] = (_Float16)s[j];
  } else if (tid < 38912) {
    int g = tid - 34816; int ln = g & 15, kb = (g >> 4) & 63, tn = g >> 10;
    const float* s = yw + (tn * 16 + ln) * 512 + kb * 8;
    _Float16* d = W2_pk + (size_t)g * 8;
#pragma unroll
    for (int j = 0; j < 8; j++) d[j] = (_Float16)s[j];
  } else if (tid < 71680) {
    int g = tid - 38912; int k = g >> 6, n8 = (g & 63) * 8;
#pragma unroll
    for (int j = 0; j < 8; j++) A_rm[(size_t)k * 512 + n8 + j] = (_Float16)xw[(size_t)(n8 + j) * 544 + k];
  }
}

// ---------------- x0 = y0 @ y2x_w^T + y2x_b  (f32, tiny) ----------------
__global__ __launch_bounds__(256) void k_x0(
    const float* __restrict__ y0, const float* __restrict__ w,
    const float* __restrict__ b, float* __restrict__ x0) {
  int tid = blockIdx.x * 256 + threadIdx.x;  // 65536 = 128*512
  int bb = tid >> 9, h = tid & 511;
  float acc = b[h];
  const float* wr = w + h * 64;
  const float* yr = y0 + bb * 64;
#pragma unroll 8
  for (int i = 0; i < 64; i++) acc += yr[i] * wr[i];
  x0[(size_t)bb * 512 + h] = acc;
}

// ---------------- squaring GEMM: P = M @ M (for A^2..A^1024) ----------------
__global__ __launch_bounds__(256) void k_sq(
    const _Float16* __restrict__ rm_in, const _Float16* __restrict__ pk_in,
    _Float16* __restrict__ rm_out, _Float16* __restrict__ pk_out) {
  int w = threadIdx.x >> 6;
  int ln = threadIdx.x & 15, g = (threadIdx.x >> 4) & 3;
  int Mb = (blockIdx.x >> 3) * 64, Nb = (blockIdx.x & 7) * 64;
  int mrow = Mb + w * 16 + ln;
  f4 acc[4];
#pragma unroll
  for (int i = 0; i < 4; i++) { f4 z = {0.f, 0.f, 0.f, 0.f}; acc[i] = z; }
  for (int k0 = 0; k0 < 512; k0 += 32) {
    h8 af = *(const h8*)(rm_in + (size_t)mrow * 512 + k0 + g * 8);
#pragma unroll
    for (int i = 0; i < 4; i++) {
      int tn = (Nb >> 4) + i;
      h8 bf = *(const h8*)(pk_in + ((size_t)(tn * 64 + (k0 >> 3) + g) * 16 + ln) * 8);
      acc[i] = MFMA16(af, bf, acc[i]);
    }
  }
  int mr0 = Mb + w * 16 + g * 4;
#pragma unroll
  for (int i = 0; i < 4; i++) {
    int n = Nb + i * 16 + ln;
#pragma unroll
    for (int r = 0; r < 4; r++) rm_out[(size_t)(mr0 + r) * 512 + n] = (_Float16)acc[i][r];
    _Float16* pd = pk_out + (size_t)((n >> 4) * 64 + (mr0 >> 3)) * 128 + (n & 15) * 8 + (mr0 & 7);
#pragma unroll
    for (int r = 0; r < 4; r++) pd[r] = (_Float16)acc[i][r];
  }
}

// ---------------- pass 1: chunk remainders (chunk 0 from x0) ----------------
// grid (4 rowblocks, 64 chunks), 512 thr. Z[j] <- state after chunk j's 32 steps.
__global__ __launch_bounds__(512) void k_pass1(
    const float* __restrict__ U, const _Float16* __restrict__ A_pk,
    const _Float16* __restrict__ Bm_pk, const float* __restrict__ xb,
    const float* __restrict__ x0, _Float16* __restrict__ Z) {
  extern __shared__ char smem[];
  char* buf0 = smem;
  char* buf1 = smem + 32768;
  const int rb = blockIdx.x, j = blockIdx.y;
  const int row0 = rb * 32;
  const int tid = threadIdx.x;
  const int w = tid >> 6, ln = tid & 15, g = (tid >> 4) & 3;
  if (j == 0) {  // chunk 0 starts from x0, not zero
    const int row = tid >> 4;
    const int c0 = (tid & 15) * 32;
    const float* s = x0 + (size_t)(row0 + row) * 512 + c0;
#pragma unroll
    for (int q = 0; q < 4; q++) {
      h8 hv;
#pragma unroll
      for (int e = 0; e < 8; e++) hv[e] = (_Float16)s[q * 8 + e];
      *(h8*)(buf0 + xoff(row, 2 * (c0 + q * 8))) = hv;
    }
    __syncthreads();
  }
  float bias[4];
  h8 bmf[4];
#pragma unroll
  for (int i = 0; i < 4; i++) {
    int tn = w * 4 + i;
    bias[i] = xb[tn * 16 + ln];
    bmf[i] = *(const h8*)(Bm_pk + ((size_t)(tn * 4 + g) * 16 + ln) * 8);
  }
  char* cur = buf0;
  char* nxt = buf1;
#pragma unroll 1
  for (int t = 0; t < S_LEN; t++) {
    f4 acc[2][4];
#pragma unroll
    for (int tm = 0; tm < 2; tm++)
#pragma unroll
      for (int i = 0; i < 4; i++) {
        f4 v = {bias[i], bias[i], bias[i], bias[i]};
        acc[tm][i] = v;
      }
    const int ku = j * S_LEN + t;
#pragma unroll
    for (int tm = 0; tm < 2; tm++) {
      const float* up = U + ((size_t)ku * 128 + row0 + tm * 16 + ln) * 32 + g * 8;
      const float4 ua = *(const float4*)up;
      const float4 ub = *(const float4*)(up + 4);
      h8 uf;
      uf[0] = (_Float16)ua.x; uf[1] = (_Float16)ua.y; uf[2] = (_Float16)ua.z; uf[3] = (_Float16)ua.w;
      uf[4] = (_Float16)ub.x; uf[5] = (_Float16)ub.y; uf[6] = (_Float16)ub.z; uf[7] = (_Float16)ub.w;
#pragma unroll
      for (int i = 0; i < 4; i++) acc[tm][i] = MFMA16(uf, bmf[i], acc[tm][i]);
    }
    if (t > 0 || j == 0) {
#pragma unroll 4
      for (int k0 = 0; k0 < 512; k0 += 32) {
        const int bc = 2 * k0 + 16 * g;
        h8 xa0 = *(const h8*)(cur + xoff(ln, bc));
        h8 xa1 = *(const h8*)(cur + xoff(16 + ln, bc));
#pragma unroll
        for (int i = 0; i < 4; i++) {
          int tn = w * 4 + i;
          h8 bf = *(const h8*)(A_pk + ((size_t)(tn * 64 + (k0 >> 3) + g) * 16 + ln) * 8);
          acc[0][i] = MFMA16(xa0, bf, acc[0][i]);
          acc[1][i] = MFMA16(xa1, bf, acc[1][i]);
        }
      }
    }
    if (t < S_LEN - 1) {
#pragma unroll
      for (int tm = 0; tm < 2; tm++)
#pragma unroll
        for (int i = 0; i < 4; i++) {
          const int n = (w * 4 + i) * 16 + ln;
#pragma unroll
          for (int r = 0; r < 4; r++) {
            const int mr = tm * 16 + g * 4 + r;
            *(_Float16*)(nxt + xoff(mr, 2 * n)) = (_Float16)acc[tm][i][r];
          }
        }
      __syncthreads();
      char* tp = cur; cur = nxt; nxt = tp;
    } else {
#pragma unroll
      for (int tm = 0; tm < 2; tm++)
#pragma unroll
        for (int i = 0; i < 4; i++) {
          const int n = (w * 4 + i) * 16 + ln;
#pragma unroll
          for (int r = 0; r < 4; r++) {
            const int mr = tm * 16 + g * 4 + r;
            Z[((size_t)j * 128 + row0 + mr) * 512 + n] = (_Float16)acc[tm][i][r];
          }
        }
    }
  }
}

// ---------------- scan sweep: Zout[j] = Zin[j-d] @ A^{32d} + Zin[j] ----------------
// grid (8 rowblocks of 16, 64 j), 512 thr, fully parallel. j<d: copy.
__global__ __launch_bounds__(512) void k_scan(
    const _Float16* __restrict__ Zin, _Float16* __restrict__ Zout,
    const _Float16* __restrict__ P_pk, int d) {
  extern __shared__ char smem[];  // 16 KB
  const int rb = blockIdx.x, j = blockIdx.y;
  const int row0 = rb * 16;
  const int tid = threadIdx.x;
  if (j < d) {
    const uint4* s = (const uint4*)(Zin + ((size_t)j * 128 + row0) * 512);
    uint4* dst = (uint4*)(Zout + ((size_t)j * 128 + row0) * 512);
#pragma unroll
    for (int q = 0; q < 2; q++) dst[tid + q * 512] = s[tid + q * 512];
    return;
  }
  const int w = tid >> 6, ln = tid & 15, g = (tid >> 4) & 3;
  {  // stage Zin[j-d] (16 rows) into swizzled LDS
    const int row = tid >> 5;
    const int c = (tid & 31) * 16;
    const _Float16* s = Zin + ((size_t)(j - d) * 128 + row0 + row) * 512 + c;
#pragma unroll
    for (int q = 0; q < 2; q++)
      *(h8*)(smem + xoff(row, 2 * (c + q * 8))) = *(const h8*)(s + q * 8);
  }
  __syncthreads();
  f4 acc[4];
#pragma unroll
  for (int i = 0; i < 4; i++) {
    const int n = (w * 4 + i) * 16 + ln;
#pragma unroll
    for (int r = 0; r < 4; r++)
      acc[i][r] = (float)Zin[((size_t)j * 128 + row0 + g * 4 + r) * 512 + n];
  }
#pragma unroll 4
  for (int k0 = 0; k0 < 512; k0 += 32) {
    h8 xa = *(const h8*)(smem + xoff(ln, 2 * k0 + 16 * g));
#pragma unroll
    for (int i = 0; i < 4; i++) {
      int tn = w * 4 + i;
      h8 bf = *(const h8*)(P_pk + ((size_t)(tn * 64 + (k0 >> 3) + g) * 16 + ln) * 8);
      acc[i] = MFMA16(xa, bf, acc[i]);
    }
  }
#pragma unroll
  for (int i = 0; i < 4; i++) {
    const int n = (w * 4 + i) * 16 + ln;
#pragma unroll
    for (int r = 0; r < 4; r++)
      Zout[((size_t)j * 128 + row0 + g * 4 + r) * 512 + n] = (_Float16)acc[i][r];
  }
}

// ---------------- pass 2: rerun chunks from true starts, fused Y projection ----------------
__global__ __launch_bounds__(512) void k_pass2(
    const float* __restrict__ U, const _Float16* __restrict__ A_pk,
    const _Float16* __restrict__ Bm_pk, const _Float16* __restrict__ W2_pk,
    const float* __restrict__ xb, const float* __restrict__ yb,
    const float* __restrict__ x0, const _Float16* __restrict__ Z,
    float* __restrict__ Y) {
  extern __shared__ char smem[];
  char* buf0 = smem;
  char* buf1 = smem + 32768;
  char* w2l = smem + 65536;
  const int rb = blockIdx.x, j = blockIdx.y;
  const int row0 = rb * 32;
  const int tid = threadIdx.x;
  const int w = tid >> 6, ln = tid & 15, g = (tid >> 4) & 3;
  {
    const uint4* s = (const uint4*)W2_pk;
    uint4* d = (uint4*)w2l;
#pragma unroll
    for (int q = 0; q < 8; q++) d[tid + q * 512] = s[tid + q * 512];
  }
  if (j == 0) {
    const int row = tid >> 4;
    const int c0 = (tid & 15) * 32;
    const float* s = x0 + (size_t)(row0 + row) * 512 + c0;
#pragma unroll
    for (int q = 0; q < 4; q++) {
      h8 hv;
#pragma unroll
      for (int e = 0; e < 8; e++) hv[e] = (_Float16)s[q * 8 + e];
      *(h8*)(buf0 + xoff(row, 2 * (c0 + q * 8))) = hv;
    }
  } else {
    const int row = tid >> 4;
    const int c0 = (tid & 15) * 32;
    const _Float16* s = Z + ((size_t)(j - 1) * 128 + row0 + row) * 512 + c0;
#pragma unroll
    for (int q = 0; q < 4; q++)
      *(h8*)(buf0 + xoff(row, 2 * (c0 + q * 8))) = *(const h8*)(s + q * 8);
  }
  __syncthreads();

  const int tmp_ = w >> 2, tnp = w & 3;
  const float ybv = yb[tnp * 16 + ln];
  auto proj = [&](const char* xs, int tg) {
    f4 p0 = {ybv, ybv, ybv, ybv};
    f4 p1 = {0.f, 0.f, 0.f, 0.f};
#pragma unroll 4
    for (int kk = 0; kk < 16; kk++) {
      const int k0 = kk * 32;
      h8 xa = *(const h8*)(xs + xoff(tmp_ * 16 + ln, 2 * k0 + 16 * g));
      h8 wf = *(const h8*)(w2l + ((size_t)(tnp * 64 + (k0 >> 3) + g) * 16 + ln) * 16);
      if (kk & 1) p1 = MFMA16(xa, wf, p1);
      else        p0 = MFMA16(xa, wf, p0);
    }
#pragma unroll
    for (int r = 0; r < 4; r++)
      Y[((size_t)tg * 128 + row0 + tmp_ * 16 + g * 4 + r) * 64 + tnp * 16 + ln] = p0[r] + p1[r];
  };

  proj(buf0, j * S_LEN);

  float bias[4];
  h8 bmf[4];
#pragma unroll
  for (int i = 0; i < 4; i++) {
    int tn = w * 4 + i;
    bias[i] = xb[tn * 16 + ln];
    bmf[i] = *(const h8*)(Bm_pk + ((size_t)(tn * 4 + g) * 16 + ln) * 8);
  }

  const int tend = (j == T_CH - 1) ? S_LEN : (S_LEN - 1);
  char* cur = buf0;
  char* nxt = buf1;
#pragma unroll 1
  for (int t = 1; t <= tend; t++) {
    f4 acc[2][4];
#pragma unroll
    for (int tm = 0; tm < 2; tm++)
#pragma unroll
      for (int i = 0; i < 4; i++) {
        f4 v = {bias[i], bias[i], bias[i], bias[i]};
        acc[tm][i] = v;
      }
    const int ku = j * S_LEN + t - 1;
#pragma unroll
    for (int tm = 0; tm < 2; tm++) {
      const float* up = U + ((size_t)ku * 128 + row0 + tm * 16 + ln) * 32 + g * 8;
      const float4 ua = *(const float4*)up;
      const float4 ub = *(const float4*)(up + 4);
      h8 uf;
      uf[0] = (_Float16)ua.x; uf[1] = (_Float16)ua.y; uf[2] = (_Float16)ua.z; uf[3] = (_Float16)ua.w;
      uf[4] = (_Float16)ub.x; uf[5] = (_Float16)ub.y; uf[6] = (_Float16)ub.z; uf[7] = (_Float16)ub.w;
#pragma unroll
      for (int i = 0; i < 4; i++) acc[tm][i] = MFMA16(uf, bmf[i], acc[tm][i]);
    }
#pragma unroll 4
    for (int k0 = 0; k0 < 512; k0 += 32) {
      const int bc = 2 * k0 + 16 * g;
      h8 xa0 = *(const h8*)(cur + xoff(ln, bc));
      h8 xa1 = *(const h8*)(cur + xoff(16 + ln, bc));
#pragma unroll
      for (int i = 0; i < 4; i++) {
        int tn = w * 4 + i;
        h8 bf = *(const h8*)(A_pk + ((size_t)(tn * 64 + (k0 >> 3) + g) * 16 + ln) * 8);
        acc[0][i] = MFMA16(xa0, bf, acc[0][i]);
        acc[1][i] = MFMA16(xa1, bf, acc[1][i]);
      }
    }
#pragma unroll
    for (int tm = 0; tm < 2; tm++)
#pragma unroll
      for (int i = 0; i < 4; i++) {
        const int n = (w * 4 + i) * 16 + ln;
#pragma unroll
        for (int r = 0; r < 4; r++) {
          const int mr = tm * 16 + g * 4 + r;
          *(_Float16*)(nxt + xoff(mr, 2 * n)) = (_Float16)acc[tm][i][r];
        }
      }
    __syncthreads();
    proj(nxt, j * S_LEN + t);
    char* tp = cur; cur = nxt; nxt = tp;
  }
}

extern "C" void kernel_launch(void* const* d_in, const int* in_sizes, int n_in,
                              void* d_out, int out_size, void* d_ws, size_t ws_size,
                              hipStream_t stream) {
  const float* y0   = (const float*)d_in[0];
  const float* U    = (const float*)d_in[1];
  const float* y2xw = (const float*)d_in[2];
  const float* y2xb = (const float*)d_in[3];
  const float* xw   = (const float*)d_in[4];
  const float* xub  = (const float*)d_in[5];
  const float* x2yw = (const float*)d_in[6];
  const float* x2yb = (const float*)d_in[7];
  float* Y = (float*)d_out;
  char* ws = (char*)d_ws;

  _Float16* A_pk  = (_Float16*)(ws);                 // 512 KB
  _Float16* Bm_pk = (_Float16*)(ws + 0x80000);       // 32 KB
  _Float16* W2_pk = (_Float16*)(ws + 0x88000);       // 64 KB
  float*    x0    = (float*)   (ws + 0x98000);       // 256 KB
  _Float16* rm_a  = (_Float16*)(ws + 0xD8000);       // 512 KB
  _Float16* rm_b  = (_Float16*)(ws + 0x158000);      // 512 KB
  _Float16* pk0   = (_Float16*)(ws + 0x1D8000);      // 10 x 512 KB: A^2..A^1024 packed
  _Float16* Zh    = (_Float16*)(ws + 0x6D8000);      // 8 MB  (64*128*512 f16)
  _Float16* Z2h   = (_Float16*)(ws + 0xED8000);      // 8 MB
  auto pk = [&](int i) { return pk0 + (size_t)i * 0x40000; };

  k_prep<<<280, 256, 0, stream>>>(xw, x2yw, A_pk, Bm_pk, W2_pk, rm_a);
  k_x0<<<256, 256, 0, stream>>>(y0, y2xw, y2xb, x0);
  // squaring chain: pk(i) = A^{2^(i+1)}; keep A^32=pk(4) .. A^1024=pk(9)
  k_sq<<<64, 256, 0, stream>>>(rm_a, A_pk,  rm_b, pk(0));
  k_sq<<<64, 256, 0, stream>>>(rm_b, pk(0), rm_a, pk(1));
  k_sq<<<64, 256, 0, stream>>>(rm_a, pk(1), rm_b, pk(2));
  k_sq<<<64, 256, 0, stream>>>(rm_b, pk(2), rm_a, pk(3));
  k_sq<<<64, 256, 0, stream>>>(rm_a, pk(3), rm_b, pk(4));
  k_sq<<<64, 256, 0, stream>>>(rm_b, pk(4), rm_a, pk(5));
  k_sq<<<64, 256, 0, stream>>>(rm_a, pk(5), rm_b, pk(6));
  k_sq<<<64, 256, 0, stream>>>(rm_b, pk(6), rm_a, pk(7));
  k_sq<<<64, 256, 0, stream>>>(rm_a, pk(7), rm_b, pk(8));
  k_sq<<<64, 256, 0, stream>>>(rm_b, pk(8), rm_a, pk(9));
  k_pass1<<<dim3(4, T_CH), 512, 65536, stream>>>(U, A_pk, Bm_pk, xub, x0, Zh);
  // Kogge-Stone scan over 64 chunk states (6 parallel sweeps, ends in Zh)
  k_scan<<<dim3(8, T_CH), 512, 16384, stream>>>(Zh,  Z2h, pk(4), 1);
  k_scan<<<dim3(8, T_CH), 512, 16384, stream>>>(Z2h, Zh,  pk(5), 2);
  k_scan<<<dim3(8, T_CH), 512, 16384, stream>>>(Zh,  Z2h, pk(6), 4);
  k_scan<<<dim3(8, T_CH), 512, 16384, stream>>>(Z2h, Zh,  pk(7), 8);
  k_scan<<<dim3(8, T_CH), 512, 16384, stream>>>(Zh,  Z2h, pk(8), 16);
  k_scan<<<dim3(8, T_CH), 512, 16384, stream>>>(Z2h, Zh,  pk(9), 32);
  k_pass2<<<dim3(4, T_CH), 512, 131072, stream>>>(U, A_pk, Bm_pk, W2_pk, xub, x2yb, x0, Zh, Y);
}

// Round 3
// 639.326 us; speedup vs baseline: 1.7839x; 1.2760x over previous
//
#include <hip/hip_runtime.h>

// Linear RNN via tap-GEMM decomposition on MI355X (gfx950).
// x_{k+1} = x_k A + u_k Bm + b ;  Y_t = x_t W2^T + yb
// NY=64 NU=32 NH=512 NHRZ=2048 B=128.  64 chunks of 32 steps.
//
// r_j   = sum_t u_{32j+t} (Bm A^{31-t}) + b*sum A^i  (+ x0 A^32 for j=0)  [k_p1: pure GEMM]
// Z     = windowed Kogge-Stone prefix (window 16; ||A^512||~1e-7 -> truncation exact)
// Y     = s_j (A^t W2T) + sum_{i<t} u_i (Bm A^{t-1-i} W2T) + ybias_t     [k_p2: pure GEMM]
// All taps built with log-depth doubling chains fused into 8 "level" launches.

#define T_CH 64

typedef _Float16 h8 __attribute__((ext_vector_type(8)));
typedef float    f4 __attribute__((ext_vector_type(4)));

__device__ __forceinline__ f4 MFMA16(h8 a, h8 b, f4 c) {
  return __builtin_amdgcn_mfma_f32_16x16x32_f16(a, b, c, 0, 0, 0);
}
__device__ __forceinline__ int xoff(int row, int bc) {  // swizzled LDS (scan only)
  return row * 1024 + (bc ^ ((row & 7) << 4));
}
// packed-B element offset for K=512 matrices: pk[tn][kb][ln][8]
__device__ __forceinline__ size_t PK512(int tn, int kb, int ln) {
  return ((size_t)(tn * 64 + kb) * 16 + ln) * 8;
}

// ---------------- prep: pack A (pk+rm), W2T->SWpk[0], R0=[Bm;b], Wst_pk[0] ----------------
__global__ __launch_bounds__(256) void k_prep(
    const float* __restrict__ xw, const float* __restrict__ yw,
    const float* __restrict__ xub,
    _Float16* __restrict__ A_pk, _Float16* __restrict__ A_rm,
    _Float16* __restrict__ SWpk, _Float16* __restrict__ R_rm,
    _Float16* __restrict__ Wst_pk) {
  int tid = blockIdx.x * 256 + threadIdx.x;
  if (tid < 32768) {  // A_pk
    int g = tid; int ln = g & 15, kb = (g >> 4) & 63, tn = g >> 10;
    const float* s = xw + (tn * 16 + ln) * 544 + kb * 8;
    _Float16* d = A_pk + (size_t)g * 8;
#pragma unroll
    for (int j = 0; j < 8; j++) d[j] = (_Float16)s[j];
  } else if (tid < 65536) {  // A_rm
    int g = tid - 32768; int k = g >> 6, n8 = (g & 63) * 8;
#pragma unroll
    for (int j = 0; j < 8; j++) A_rm[(size_t)k * 512 + n8 + j] = (_Float16)xw[(size_t)(n8 + j) * 544 + k];
  } else if (tid < 69632) {  // SWpk[0] = W2T packed
    int g = tid - 65536; int ln = g & 15, kb = (g >> 4) & 63, tn = g >> 10;
    const float* s = yw + (tn * 16 + ln) * 512 + kb * 8;
    _Float16* d = SWpk + (size_t)g * 8;
#pragma unroll
    for (int j = 0; j < 8; j++) d[j] = (_Float16)s[j];
  } else if (tid < 72704) {  // R_rm[0] = [Bm(32); b(1); 0(15)]  [48x512]
    int g = tid - 69632; int row = g >> 6, n8 = (g & 63) * 8;
#pragma unroll
    for (int j = 0; j < 8; j++) {
      float v = 0.f;
      if (row < 32) v = xw[(size_t)(n8 + j) * 544 + 512 + row];
      else if (row == 32) v = xub[n8 + j];
      R_rm[(size_t)row * 512 + n8 + j] = (_Float16)v;
    }
  } else if (tid < 74752) {  // Wst_pk[0] = packed Bm (K=32)
    int g = tid - 72704; int ln = g & 15, gg = (g >> 4) & 3, tn = g >> 6;
    _Float16* d = Wst_pk + (size_t)g * 8;
#pragma unroll
    for (int j = 0; j < 8; j++) d[j] = (_Float16)xw[(size_t)(tn * 16 + ln) * 544 + 512 + gg * 8 + j];
  }
}

// ---------------- x0h = f16(y0 @ y2x_w^T + y2x_b) ----------------
__global__ __launch_bounds__(256) void k_x0(
    const float* __restrict__ y0, const float* __restrict__ w,
    const float* __restrict__ b, _Float16* __restrict__ x0h) {
  int tid = blockIdx.x * 256 + threadIdx.x;  // 65536 = 128*512
  int bb = tid >> 9, h = tid & 511;
  float acc = b[h];
  const float* wr = w + h * 64;
  const float* yr = y0 + bb * 64;
#pragma unroll 8
  for (int i = 0; i < 64; i++) acc += yr[i] * wr[i];
  x0h[(size_t)bb * 512 + h] = (_Float16)acc;
}

// ---------------- fused chain level: sq (A^{2^{m+1}}) | R-taps | SW-taps ----------------
// blocks [0,64): pw_out = pw_rm @ pw_pk (rm+pk out)
// blocks [64,64+nR): R[k+2^m] = R[k] @ pw_pk  -> R_rm dst + Wst_pk dst
// rest (8*nSW):      SW[t+off] = pw_rm @ SWpk[t] (pk out)
__global__ __launch_bounds__(256) void k_chain(
    const _Float16* __restrict__ rm_in, const _Float16* __restrict__ pk_in,
    _Float16* __restrict__ rm_out, _Float16* __restrict__ pk_out,
    _Float16* __restrict__ R_rm, _Float16* __restrict__ Wst_pk,
    _Float16* __restrict__ SWpk, int nR, int nSW, int off) {
  const int bid = blockIdx.x;
  const int tid = threadIdx.x;
  const int w = tid >> 6, ln = tid & 15, g = (tid >> 4) & 3;
  if (bid < 64) {  // ---- squaring GEMM (identical to verified k_sq) ----
    int Mb = (bid >> 3) * 64, Nb = (bid & 7) * 64;
    int mrow = Mb + w * 16 + ln;
    f4 acc[4];
#pragma unroll
    for (int i = 0; i < 4; i++) { f4 z = {0.f, 0.f, 0.f, 0.f}; acc[i] = z; }
    for (int k0 = 0; k0 < 512; k0 += 32) {
      h8 af = *(const h8*)(rm_in + (size_t)mrow * 512 + k0 + g * 8);
#pragma unroll
      for (int i = 0; i < 4; i++) {
        h8 bf = *(const h8*)(pk_in + PK512((Nb >> 4) + i, (k0 >> 3) + g, ln));
        acc[i] = MFMA16(af, bf, acc[i]);
      }
    }
    int mr0 = Mb + w * 16 + g * 4;
#pragma unroll
    for (int i = 0; i < 4; i++) {
      int n = Nb + i * 16 + ln;
#pragma unroll
      for (int r = 0; r < 4; r++) rm_out[(size_t)(mr0 + r) * 512 + n] = (_Float16)acc[i][r];
      _Float16* pd = pk_out + (size_t)((n >> 4) * 64 + (mr0 >> 3)) * 128 + (n & 15) * 8 + (mr0 & 7);
#pragma unroll
      for (int r = 0; r < 4; r++) pd[r] = (_Float16)acc[i][r];
    }
  } else if (bid < 64 + nR) {  // ---- R chain: [48x512] = R[k] @ pw ----
    const int k = bid - 64;
    const _Float16* src = R_rm + (size_t)k * 24576;
    _Float16* dst = R_rm + (size_t)(k + off) * 24576;
    _Float16* wpk = Wst_pk + (size_t)(k + off) * 16384;
    f4 acc[3][8];
#pragma unroll
    for (int mt = 0; mt < 3; mt++)
#pragma unroll
      for (int i = 0; i < 8; i++) { f4 z = {0.f, 0.f, 0.f, 0.f}; acc[mt][i] = z; }
    for (int k0 = 0; k0 < 512; k0 += 32) {
      h8 af[3];
#pragma unroll
      for (int mt = 0; mt < 3; mt++)
        af[mt] = *(const h8*)(src + (size_t)(mt * 16 + ln) * 512 + k0 + g * 8);
#pragma unroll
      for (int i = 0; i < 8; i++) {
        h8 bf = *(const h8*)(pk_in + PK512(w * 8 + i, (k0 >> 3) + g, ln));
#pragma unroll
        for (int mt = 0; mt < 3; mt++) acc[mt][i] = MFMA16(af[mt], bf, acc[mt][i]);
      }
    }
#pragma unroll
    for (int mt = 0; mt < 3; mt++)
#pragma unroll
      for (int i = 0; i < 8; i++) {
        int tn = w * 8 + i, col = tn * 16 + ln;
        int r0 = mt * 16 + g * 4;
#pragma unroll
        for (int r = 0; r < 4; r++) dst[(size_t)(r0 + r) * 512 + col] = (_Float16)acc[mt][i][r];
        if (mt < 2) {
          _Float16* pd = wpk + ((size_t)(tn * 4 + (r0 >> 3)) * 16 + ln) * 8 + (r0 & 7);
#pragma unroll
          for (int r = 0; r < 4; r++) pd[r] = (_Float16)acc[mt][i][r];
        }
      }
  } else {  // ---- SW chain: SW[t+off] = pw_rm @ SW[t], block covers 64 rows ----
    const int q = bid - 64 - nR;
    const int t = q >> 3, mb = q & 7;
    const _Float16* src = SWpk + (size_t)t * 32768;
    _Float16* dst = SWpk + (size_t)(t + off) * 32768;
    f4 acc[4];
#pragma unroll
    for (int c = 0; c < 4; c++) { f4 z = {0.f, 0.f, 0.f, 0.f}; acc[c] = z; }
    const int rbase = mb * 64 + w * 16;
    for (int k0 = 0; k0 < 512; k0 += 32) {
      h8 af = *(const h8*)(rm_in + (size_t)(rbase + ln) * 512 + k0 + g * 8);
#pragma unroll
      for (int c = 0; c < 4; c++) {
        h8 bf = *(const h8*)(src + PK512(c, (k0 >> 3) + g, ln));
        acc[c] = MFMA16(af, bf, acc[c]);
      }
    }
    const int r0 = rbase + g * 4;
#pragma unroll
    for (int c = 0; c < 4; c++) {
      _Float16* pd = dst + ((size_t)(c * 64 + (r0 >> 3)) * 16 + ln) * 8 + (r0 & 7);
#pragma unroll
      for (int r = 0; r < 4; r++) pd[r] = (_Float16)acc[c][r];
    }
  }
}

// ---------------- G[k] = (Bm A^k) @ W2T  [32x64], packed K=32 ----------------
__global__ __launch_bounds__(256) void k_gk(
    const _Float16* __restrict__ R_rm, const _Float16* __restrict__ SWpk0,
    _Float16* __restrict__ Gpk) {
  const int tap = blockIdx.x;
  const int tid = threadIdx.x;
  const int w = tid >> 6, ln = tid & 15, g = (tid >> 4) & 3;
  const int mt = w & 1, cb = (w >> 1) * 2;
  const _Float16* src = R_rm + (size_t)tap * 24576;
  f4 acc[2];
#pragma unroll
  for (int c = 0; c < 2; c++) { f4 z = {0.f, 0.f, 0.f, 0.f}; acc[c] = z; }
  for (int k0 = 0; k0 < 512; k0 += 32) {
    h8 af = *(const h8*)(src + (size_t)(mt * 16 + ln) * 512 + k0 + g * 8);
#pragma unroll
    for (int c = 0; c < 2; c++) {
      h8 bf = *(const h8*)(SWpk0 + PK512(cb + c, (k0 >> 3) + g, ln));
      acc[c] = MFMA16(af, bf, acc[c]);
    }
  }
  const int r0 = mt * 16 + g * 4;
#pragma unroll
  for (int c = 0; c < 2; c++) {
    _Float16* pd = Gpk + (size_t)tap * 2048 + ((size_t)((cb + c) * 4 + (r0 >> 3)) * 16 + ln) * 8 + (r0 & 7);
#pragma unroll
    for (int r = 0; r < 4; r++) pd[r] = (_Float16)acc[c][r];
  }
}

// ---------------- misc: gb[i]=bA^i W2T -> ybias[t]; bias32 ----------------
__global__ __launch_bounds__(256) void k_misc(
    const _Float16* __restrict__ R_rm, const float* __restrict__ yw,
    const float* __restrict__ yb, float* __restrict__ ybias,
    float* __restrict__ bias32) {
  __shared__ float gb[2048];
  const int tid = threadIdx.x;
  for (int idx = tid; idx < 2048; idx += 256) {
    int i = idx >> 6, c = idx & 63;
    const _Float16* br = R_rm + (size_t)i * 24576 + 32 * 512;
    const float* wc = yw + c * 512;
    float s = 0.f;
#pragma unroll 8
    for (int h = 0; h < 512; h++) s += (float)br[h] * wc[h];
    gb[idx] = s;
  }
  __syncthreads();
  for (int idx = tid; idx < 2048; idx += 256) {
    int t = (idx >> 6) + 1, c = idx & 63;
    float s = yb[c];
    for (int i = 0; i < t; i++) s += gb[i * 64 + c];
    ybias[t * 64 + c] = s;
  }
  for (int n = tid; n < 512; n += 256) {
    float s = 0.f;
#pragma unroll
    for (int i = 0; i < 32; i++) s += (float)R_rm[(size_t)i * 24576 + 32 * 512 + n];
    bias32[n] = s;
  }
}

// ---------------- Y[0] = x0 @ W2T + yb ----------------
__global__ __launch_bounds__(512) void k_y0(
    const _Float16* __restrict__ x0h, const _Float16* __restrict__ SWpk0,
    const float* __restrict__ yb, float* __restrict__ Y) {
  const int tid = threadIdx.x;
  const int w = tid >> 6, ln = tid & 15, g = (tid >> 4) & 3;
  f4 acc[4];
#pragma unroll
  for (int c = 0; c < 4; c++) { f4 z = {0.f, 0.f, 0.f, 0.f}; acc[c] = z; }
  for (int k0 = 0; k0 < 512; k0 += 32) {
    h8 af = *(const h8*)(x0h + (size_t)(w * 16 + ln) * 512 + k0 + g * 8);
#pragma unroll
    for (int c = 0; c < 4; c++) {
      h8 bf = *(const h8*)(SWpk0 + PK512(c, (k0 >> 3) + g, ln));
      acc[c] = MFMA16(af, bf, acc[c]);
    }
  }
#pragma unroll
  for (int c = 0; c < 4; c++) {
    int col = c * 16 + ln;
#pragma unroll
    for (int r = 0; r < 4; r++)
      Y[(size_t)(w * 16 + g * 4 + r) * 64 + col] = acc[c][r] + yb[col];
  }
}

// ---------------- pass 1: r_j = Ublk_j @ Wst + bias32 (+ x0 A^32 for j=0) ----------------
// grid (4 rowblocks of 32, 64 chunks), 512 thr.
__global__ __launch_bounds__(512) void k_p1(
    const float* __restrict__ U, const _Float16* __restrict__ Wst_pk,
    const _Float16* __restrict__ x0h, const _Float16* __restrict__ A32_pk,
    const float* __restrict__ bias32, _Float16* __restrict__ Zh) {
  const int rb = blockIdx.x, j = blockIdx.y;
  const int row0 = rb * 32;
  const int tid = threadIdx.x;
  const int w = tid >> 6, ln = tid & 15, g = (tid >> 4) & 3;
  f4 acc[2][4];
#pragma unroll
  for (int tm = 0; tm < 2; tm++)
#pragma unroll
    for (int i = 0; i < 4; i++) { f4 z = {0.f, 0.f, 0.f, 0.f}; acc[tm][i] = z; }
#pragma unroll 4
  for (int t = 0; t < 32; t++) {
    const _Float16* wp = Wst_pk + (size_t)(31 - t) * 16384;
    h8 uf[2];
#pragma unroll
    for (int tm = 0; tm < 2; tm++) {
      const float* up = U + ((size_t)(j * 32 + t) * 128 + row0 + tm * 16 + ln) * 32 + g * 8;
      const float4 ua = *(const float4*)up;
      const float4 ub = *(const float4*)(up + 4);
      h8 v;
      v[0] = (_Float16)ua.x; v[1] = (_Float16)ua.y; v[2] = (_Float16)ua.z; v[3] = (_Float16)ua.w;
      v[4] = (_Float16)ub.x; v[5] = (_Float16)ub.y; v[6] = (_Float16)ub.z; v[7] = (_Float16)ub.w;
      uf[tm] = v;
    }
#pragma unroll
    for (int i = 0; i < 4; i++) {
      h8 bf = *(const h8*)(wp + ((size_t)((w * 4 + i) * 4 + g) * 16 + ln) * 8);
#pragma unroll
      for (int tm = 0; tm < 2; tm++) acc[tm][i] = MFMA16(uf[tm], bf, acc[tm][i]);
    }
  }
  if (j == 0) {  // seed: += x0 @ A^32
    for (int k0 = 0; k0 < 512; k0 += 32) {
      h8 af[2];
#pragma unroll
      for (int tm = 0; tm < 2; tm++)
        af[tm] = *(const h8*)(x0h + (size_t)(row0 + tm * 16 + ln) * 512 + k0 + g * 8);
#pragma unroll
      for (int i = 0; i < 4; i++) {
        h8 bf = *(const h8*)(A32_pk + PK512(w * 4 + i, (k0 >> 3) + g, ln));
#pragma unroll
        for (int tm = 0; tm < 2; tm++) acc[tm][i] = MFMA16(af[tm], bf, acc[tm][i]);
      }
    }
  }
#pragma unroll
  for (int tm = 0; tm < 2; tm++)
#pragma unroll
    for (int i = 0; i < 4; i++) {
      const int n = (w * 4 + i) * 16 + ln;
      const float bz = bias32[n];
#pragma unroll
      for (int r = 0; r < 4; r++) {
        const int mr = tm * 16 + g * 4 + r;
        Zh[((size_t)j * 128 + row0 + mr) * 512 + n] = (_Float16)(acc[tm][i][r] + bz);
      }
    }
}

// ---------------- scan sweep: Zout[j] = Zin[j-d] @ A^{32d} + Zin[j] ----------------
__global__ __launch_bounds__(512) void k_scan(
    const _Float16* __restrict__ Zin, _Float16* __restrict__ Zout,
    const _Float16* __restrict__ P_pk, int d) {
  extern __shared__ char smem[];  // 16 KB
  const int rb = blockIdx.x, j = blockIdx.y;
  const int row0 = rb * 16;
  const int tid = threadIdx.x;
  if (j < d) {
    const uint4* s = (const uint4*)(Zin + ((size_t)j * 128 + row0) * 512);
    uint4* dst = (uint4*)(Zout + ((size_t)j * 128 + row0) * 512);
#pragma unroll
    for (int q = 0; q < 2; q++) dst[tid + q * 512] = s[tid + q * 512];
    return;
  }
  const int w = tid >> 6, ln = tid & 15, g = (tid >> 4) & 3;
  {
    const int row = tid >> 5;
    const int c = (tid & 31) * 16;
    const _Float16* s = Zin + ((size_t)(j - d) * 128 + row0 + row) * 512 + c;
#pragma unroll
    for (int q = 0; q < 2; q++)
      *(h8*)(smem + xoff(row, 2 * (c + q * 8))) = *(const h8*)(s + q * 8);
  }
  __syncthreads();
  f4 acc[4];
#pragma unroll
  for (int i = 0; i < 4; i++) {
    const int n = (w * 4 + i) * 16 + ln;
#pragma unroll
    for (int r = 0; r < 4; r++)
      acc[i][r] = (float)Zin[((size_t)j * 128 + row0 + g * 4 + r) * 512 + n];
  }
#pragma unroll 4
  for (int k0 = 0; k0 < 512; k0 += 32) {
    h8 xa = *(const h8*)(smem + xoff(ln, 2 * k0 + 16 * g));
#pragma unroll
    for (int i = 0; i < 4; i++) {
      h8 bf = *(const h8*)(P_pk + PK512(w * 4 + i, (k0 >> 3) + g, ln));
      acc[i] = MFMA16(xa, bf, acc[i]);
    }
  }
#pragma unroll
  for (int i = 0; i < 4; i++) {
    const int n = (w * 4 + i) * 16 + ln;
#pragma unroll
    for (int r = 0; r < 4; r++)
      Zout[((size_t)j * 128 + row0 + g * 4 + r) * 512 + n] = (_Float16)acc[i][r];
  }
}

// ---------------- pass 2: Y[32j+t] = s_j SW[t] + sum_{i<t} u_i G[t-1-i] + ybias[t] ----------------
// grid (8 t-groups of 4, 64 chunks), 512 thr, no LDS, no barriers.
__global__ __launch_bounds__(512) void k_p2(
    const float* __restrict__ U, const _Float16* __restrict__ Zh,
    const _Float16* __restrict__ x0h, const _Float16* __restrict__ SWpk,
    const _Float16* __restrict__ Gpk, const float* __restrict__ ybias,
    float* __restrict__ Y) {
  const int nb = blockIdx.x, j = blockIdx.y;
  const int tid = threadIdx.x;
  const int w = tid >> 6, ln = tid & 15, g = (tid >> 4) & 3;
  const int mh = w >> 2;                  // 0/1: rows mh*64
  const int tw = nb * 4 + (w & 3) + 1;    // 1..32
  const _Float16* S = (j == 0) ? x0h : (Zh + (size_t)(j - 1) * 65536);
  const _Float16* SW = SWpk + (size_t)tw * 32768;
  f4 acc[4][4];
#pragma unroll
  for (int mt = 0; mt < 4; mt++)
#pragma unroll
    for (int c = 0; c < 4; c++) { f4 z = {0.f, 0.f, 0.f, 0.f}; acc[mt][c] = z; }
  // s-part: K=512
  for (int k0 = 0; k0 < 512; k0 += 32) {
    h8 af[4];
#pragma unroll
    for (int mt = 0; mt < 4; mt++)
      af[mt] = *(const h8*)(S + (size_t)(mh * 64 + mt * 16 + ln) * 512 + k0 + g * 8);
#pragma unroll
    for (int c = 0; c < 4; c++) {
      h8 bf = *(const h8*)(SW + PK512(c, (k0 >> 3) + g, ln));
#pragma unroll
      for (int mt = 0; mt < 4; mt++) acc[mt][c] = MFMA16(af[mt], bf, acc[mt][c]);
    }
  }
  // u-part: taps i=0..tw-1
#pragma unroll 4
  for (int i = 0; i < tw; i++) {
    h8 uf[4];
#pragma unroll
    for (int mt = 0; mt < 4; mt++) {
      const float* up = U + ((size_t)(j * 32 + i) * 128 + mh * 64 + mt * 16 + ln) * 32 + g * 8;
      const float4 ua = *(const float4*)up;
      const float4 ub = *(const float4*)(up + 4);
      h8 v;
      v[0] = (_Float16)ua.x; v[1] = (_Float16)ua.y; v[2] = (_Float16)ua.z; v[3] = (_Float16)ua.w;
      v[4] = (_Float16)ub.x; v[5] = (_Float16)ub.y; v[6] = (_Float16)ub.z; v[7] = (_Float16)ub.w;
      uf[mt] = v;
    }
    const _Float16* gp = Gpk + (size_t)(tw - 1 - i) * 2048;
#pragma unroll
    for (int c = 0; c < 4; c++) {
      h8 bf = *(const h8*)(gp + ((size_t)(c * 4 + g) * 16 + ln) * 8);
#pragma unroll
      for (int mt = 0; mt < 4; mt++) acc[mt][c] = MFMA16(uf[mt], bf, acc[mt][c]);
    }
  }
  // epilogue
  const size_t ybase = (size_t)(j * 32 + tw) * 128;
#pragma unroll
  for (int mt = 0; mt < 4; mt++)
#pragma unroll
    for (int c = 0; c < 4; c++) {
      const int col = c * 16 + ln;
      const float yv = ybias[tw * 64 + col];
#pragma unroll
      for (int r = 0; r < 4; r++) {
        const int row = mh * 64 + mt * 16 + g * 4 + r;
        Y[(ybase + row) * 64 + col] = acc[mt][c][r] + yv;
      }
    }
}

extern "C" void kernel_launch(void* const* d_in, const int* in_sizes, int n_in,
                              void* d_out, int out_size, void* d_ws, size_t ws_size,
                              hipStream_t stream) {
  const float* y0   = (const float*)d_in[0];
  const float* U    = (const float*)d_in[1];
  const float* y2xw = (const float*)d_in[2];
  const float* y2xb = (const float*)d_in[3];
  const float* xw   = (const float*)d_in[4];
  const float* xub  = (const float*)d_in[5];
  const float* x2yw = (const float*)d_in[6];
  const float* x2yb = (const float*)d_in[7];
  float* Y = (float*)d_out;
  char* ws = (char*)d_ws;

  // Z2 region [0, 8MB) aliases transient chain buffers (dead before first scan write).
  _Float16* A_rm  = (_Float16*)(ws + 0x000000);
  _Float16* A_pk  = (_Float16*)(ws + 0x080000);
  auto rm = [&](int m) { return (_Float16*)(ws + 0x100000 + (size_t)(m - 1) * 0x80000); }; // m=1..7
  auto pkL = [&](int m) { return (_Float16*)(ws + 0x480000 + (size_t)(m - 1) * 0x80000); }; // m=1..4
  _Float16* R_rm  = (_Float16*)(ws + 0x680000);   // 32 x [48x512] = 1.5 MB -> 0x800000
  _Float16* Z2    = (_Float16*)(ws + 0x000000);   // scan ping buffer (8 MB)
  _Float16* Zh    = (_Float16*)(ws + 0x800000);   // 8 MB
  auto pkH = [&](int m) { return (_Float16*)(ws + 0x1000000 + (size_t)(m - 5) * 0x80000); }; // m=5..8
  _Float16* Wst_pk = (_Float16*)(ws + 0x1200000); // 1 MB
  _Float16* SWpk   = (_Float16*)(ws + 0x1300000); // 33 x 64KB
  _Float16* Gpk    = (_Float16*)(ws + 0x1510000); // 128 KB
  float*    ybias  = (float*)   (ws + 0x1530000);
  float*    bias32 = (float*)   (ws + 0x1534000);
  _Float16* x0h    = (_Float16*)(ws + 0x1538000); // 128 KB -> total 0x1558000 (22.3 MB)
  auto pw_rm = [&](int m) { return m == 0 ? A_rm : rm(m); };
  auto pw_pk = [&](int m) { return m == 0 ? A_pk : (m <= 4 ? pkL(m) : pkH(m)); };

  k_prep<<<292, 256, 0, stream>>>(xw, x2yw, xub, A_pk, A_rm, SWpk, R_rm, Wst_pk);
  k_x0<<<256, 256, 0, stream>>>(y0, y2xw, y2xb, x0h);
  // fused chains: levels 0..4 (sq + R + SW), 5 (sq + SW[32]), 6..7 (sq only)
  for (int m = 0; m < 8; m++) {
    int nR = (m <= 4) ? (1 << m) : 0;
    int nSW = (m <= 4) ? (1 << m) : (m == 5 ? 1 : 0);
    int off = (m == 5) ? 32 : (1 << m);
    _Float16* rmo = (m == 7) ? rm(1) : rm(m + 1);  // A^256 rm unused -> dummy slot
    k_chain<<<64 + nR + 8 * nSW, 256, 0, stream>>>(
        pw_rm(m), pw_pk(m), rmo, pw_pk(m + 1), R_rm, Wst_pk, SWpk, nR, nSW, off);
  }
  k_gk<<<32, 256, 0, stream>>>(R_rm, SWpk, Gpk);
  k_misc<<<1, 256, 0, stream>>>(R_rm, x2yw, x2yb, ybias, bias32);
  k_y0<<<1, 512, 0, stream>>>(x0h, SWpk, x2yb, Y);
  k_p1<<<dim3(4, T_CH), 512, 0, stream>>>(U, Wst_pk, x0h, pkH(5), bias32, Zh);
  // windowed Kogge-Stone (window 16; ||A^512|| ~ 1.6e-7 -> deeper terms vanish)
  k_scan<<<dim3(8, T_CH), 512, 16384, stream>>>(Zh, Z2, pkH(5), 1);
  k_scan<<<dim3(8, T_CH), 512, 16384, stream>>>(Z2, Zh, pkH(6), 2);
  k_scan<<<dim3(8, T_CH), 512, 16384, stream>>>(Zh, Z2, pkH(7), 4);
  k_scan<<<dim3(8, T_CH), 512, 16384, stream>>>(Z2, Zh, pkH(8), 8);
  k_p2<<<dim3(8, T_CH), 512, 0, stream>>>(U, Zh, x0h, SWpk, Gpk, ybias, Y);
}

// Round 4
// 608.376 us; speedup vs baseline: 1.8747x; 1.0509x over previous
//
#include <hip/hip_runtime.h>

// Linear RNN via tap-GEMM decomposition on MI355X (gfx950).
// x_{k+1} = x_k A + u_k Bm + b ;  Y_t = x_t W2^T + yb
// NY=64 NU=32 NH=512 NHRZ=2048 B=128.  64 chunks of 32 steps.
//
// r_j = sum_t u_{32j+t} (Bm A^{31-t}) + bias32 (+ x0 A^32, j=0)   [k_p1]
// Z   = windowed Kogge-Stone prefix (window 16)                   [k_scan x4]
// Y[32j+t] = s_j (A^t W2T) + sum_{i<t} u_i G[t-1-i] + ybias[t]    [k_p2]
// k_p2: t-paired blocks (t, 33-t): K-work = 2080 const -> perfect balance;
// XCD-bijective chunk grouping so a chunk's 16 blocks share one L2.

#define T_CH 64

typedef _Float16 h8 __attribute__((ext_vector_type(8)));
typedef float    f4 __attribute__((ext_vector_type(4)));

__device__ __forceinline__ f4 MFMA16(h8 a, h8 b, f4 c) {
  return __builtin_amdgcn_mfma_f32_16x16x32_f16(a, b, c, 0, 0, 0);
}
__device__ __forceinline__ int xoff(int row, int bc) {  // swizzled LDS (scan only)
  return row * 1024 + (bc ^ ((row & 7) << 4));
}
__device__ __forceinline__ size_t PK512(int tn, int kb, int ln) {
  return ((size_t)(tn * 64 + kb) * 16 + ln) * 8;
}

// ---------------- prep: pack A (pk+rm), W2T->SWpk[0], R0=[Bm;b], Wst_pk[0], x0h ----------------
__global__ __launch_bounds__(256) void k_prep0(
    const float* __restrict__ xw, const float* __restrict__ yw,
    const float* __restrict__ xub, const float* __restrict__ y0,
    const float* __restrict__ y2xw, const float* __restrict__ y2xb,
    _Float16* __restrict__ A_pk, _Float16* __restrict__ A_rm,
    _Float16* __restrict__ SWpk, _Float16* __restrict__ R_rm,
    _Float16* __restrict__ Wst_pk, _Float16* __restrict__ x0h) {
  int tid = blockIdx.x * 256 + threadIdx.x;
  if (tid < 32768) {  // A_pk
    int g = tid; int ln = g & 15, kb = (g >> 4) & 63, tn = g >> 10;
    const float* s = xw + (tn * 16 + ln) * 544 + kb * 8;
    _Float16* d = A_pk + (size_t)g * 8;
#pragma unroll
    for (int j = 0; j < 8; j++) d[j] = (_Float16)s[j];
  } else if (tid < 65536) {  // A_rm
    int g = tid - 32768; int k = g >> 6, n8 = (g & 63) * 8;
#pragma unroll
    for (int j = 0; j < 8; j++) A_rm[(size_t)k * 512 + n8 + j] = (_Float16)xw[(size_t)(n8 + j) * 544 + k];
  } else if (tid < 69632) {  // SWpk[0] = W2T packed
    int g = tid - 65536; int ln = g & 15, kb = (g >> 4) & 63, tn = g >> 10;
    const float* s = yw + (tn * 16 + ln) * 512 + kb * 8;
    _Float16* d = SWpk + (size_t)g * 8;
#pragma unroll
    for (int j = 0; j < 8; j++) d[j] = (_Float16)s[j];
  } else if (tid < 72704) {  // R_rm[0] = [Bm(32); b(1); 0(15)]
    int g = tid - 69632; int row = g >> 6, n8 = (g & 63) * 8;
#pragma unroll
    for (int j = 0; j < 8; j++) {
      float v = 0.f;
      if (row < 32) v = xw[(size_t)(n8 + j) * 544 + 512 + row];
      else if (row == 32) v = xub[n8 + j];
      R_rm[(size_t)row * 512 + n8 + j] = (_Float16)v;
    }
  } else if (tid < 74752) {  // Wst_pk[0] = packed Bm (K=32)
    int g = tid - 72704; int ln = g & 15, gg = (g >> 4) & 3, tn = g >> 6;
    _Float16* d = Wst_pk + (size_t)g * 8;
#pragma unroll
    for (int j = 0; j < 8; j++) d[j] = (_Float16)xw[(size_t)(tn * 16 + ln) * 544 + 512 + gg * 8 + j];
  } else if (tid < 140288) {  // x0h = f16(y0 @ y2x_w^T + y2x_b)
    int id = tid - 74752;
    int bb = id >> 9, h = id & 511;
    float acc = y2xb[h];
    const float* wr = y2xw + h * 64;
    const float* yr = y0 + bb * 64;
#pragma unroll 8
    for (int i = 0; i < 64; i++) acc += yr[i] * wr[i];
    x0h[(size_t)bb * 512 + h] = (_Float16)acc;
  }
}

// ---------------- fused chain level: sq (A^{2^{m+1}}) | R-taps | SW-taps ----------------
// blocks [0,256): 32x32 tiles of pw_out = pw_rm @ pw_pk  (4x parallelism of old 64-block)
// blocks [256,256+nR): R[k+2^m] = R[k] @ pw_pk ; rest (8*nSW): SW[t+off] = pw_rm @ SW[t]
__global__ __launch_bounds__(256) void k_chain(
    const _Float16* __restrict__ rm_in, const _Float16* __restrict__ pk_in,
    _Float16* __restrict__ rm_out, _Float16* __restrict__ pk_out,
    _Float16* __restrict__ R_rm, _Float16* __restrict__ Wst_pk,
    _Float16* __restrict__ SWpk, int nR, int nSW, int off) {
  const int bid = blockIdx.x;
  const int tid = threadIdx.x;
  const int w = tid >> 6, ln = tid & 15, g = (tid >> 4) & 3;
  if (bid < 256) {  // ---- squaring GEMM, 32x32 tile, 1 MFMA/wave/k-step ----
    const int Mb = (bid >> 4) * 32, Nb = (bid & 15) * 32;
    const int mt = w >> 1, nt = w & 1;
    const int mrow = Mb + mt * 16 + ln;
    f4 acc = {0.f, 0.f, 0.f, 0.f};
    for (int k0 = 0; k0 < 512; k0 += 32) {
      h8 af = *(const h8*)(rm_in + (size_t)mrow * 512 + k0 + g * 8);
      h8 bf = *(const h8*)(pk_in + PK512((Nb >> 4) + nt, (k0 >> 3) + g, ln));
      acc = MFMA16(af, bf, acc);
    }
    const int mr0 = Mb + mt * 16 + g * 4;
    const int n = Nb + nt * 16 + ln;
#pragma unroll
    for (int r = 0; r < 4; r++) rm_out[(size_t)(mr0 + r) * 512 + n] = (_Float16)acc[r];
    _Float16* pd = pk_out + (size_t)((n >> 4) * 64 + (mr0 >> 3)) * 128 + (n & 15) * 8 + (mr0 & 7);
#pragma unroll
    for (int r = 0; r < 4; r++) pd[r] = (_Float16)acc[r];
  } else if (bid < 256 + nR) {  // ---- R chain: [48x512] = R[k] @ pw ----
    const int k = bid - 256;
    const _Float16* src = R_rm + (size_t)k * 24576;
    _Float16* dst = R_rm + (size_t)(k + off) * 24576;
    _Float16* wpk = Wst_pk + (size_t)(k + off) * 16384;
    f4 acc[3][8];
#pragma unroll
    for (int mt = 0; mt < 3; mt++)
#pragma unroll
      for (int i = 0; i < 8; i++) { f4 z = {0.f, 0.f, 0.f, 0.f}; acc[mt][i] = z; }
    for (int k0 = 0; k0 < 512; k0 += 32) {
      h8 af[3];
#pragma unroll
      for (int mt = 0; mt < 3; mt++)
        af[mt] = *(const h8*)(src + (size_t)(mt * 16 + ln) * 512 + k0 + g * 8);
#pragma unroll
      for (int i = 0; i < 8; i++) {
        h8 bf = *(const h8*)(pk_in + PK512(w * 8 + i, (k0 >> 3) + g, ln));
#pragma unroll
        for (int mt = 0; mt < 3; mt++) acc[mt][i] = MFMA16(af[mt], bf, acc[mt][i]);
      }
    }
#pragma unroll
    for (int mt = 0; mt < 3; mt++)
#pragma unroll
      for (int i = 0; i < 8; i++) {
        int tn = w * 8 + i, col = tn * 16 + ln;
        int r0 = mt * 16 + g * 4;
#pragma unroll
        for (int r = 0; r < 4; r++) dst[(size_t)(r0 + r) * 512 + col] = (_Float16)acc[mt][i][r];
        if (mt < 2) {
          _Float16* pd = wpk + ((size_t)(tn * 4 + (r0 >> 3)) * 16 + ln) * 8 + (r0 & 7);
#pragma unroll
          for (int r = 0; r < 4; r++) pd[r] = (_Float16)acc[mt][i][r];
        }
      }
  } else {  // ---- SW chain: SW[t+off] = pw_rm @ SW[t] ----
    const int q = bid - 256 - nR;
    const int t = q >> 3, mb = q & 7;
    const _Float16* src = SWpk + (size_t)t * 32768;
    _Float16* dst = SWpk + (size_t)(t + off) * 32768;
    f4 acc[4];
#pragma unroll
    for (int c = 0; c < 4; c++) { f4 z = {0.f, 0.f, 0.f, 0.f}; acc[c] = z; }
    const int rbase = mb * 64 + w * 16;
    for (int k0 = 0; k0 < 512; k0 += 32) {
      h8 af = *(const h8*)(rm_in + (size_t)(rbase + ln) * 512 + k0 + g * 8);
#pragma unroll
      for (int c = 0; c < 4; c++) {
        h8 bf = *(const h8*)(src + PK512(c, (k0 >> 3) + g, ln));
        acc[c] = MFMA16(af, bf, acc[c]);
      }
    }
    const int r0 = rbase + g * 4;
#pragma unroll
    for (int c = 0; c < 4; c++) {
      _Float16* pd = dst + ((size_t)(c * 64 + (r0 >> 3)) * 16 + ln) * 8 + (r0 & 7);
#pragma unroll
      for (int r = 0; r < 4; r++) pd[r] = (_Float16)acc[c][r];
    }
  }
}

// ---------------- aux: Gpk taps (blocks 0..31) | ybias+bias32 (32) | Y[0] (33) ----------------
__global__ __launch_bounds__(512) void k_aux(
    const _Float16* __restrict__ R_rm, const _Float16* __restrict__ SWpk0,
    _Float16* __restrict__ Gpk, const float* __restrict__ yw,
    const float* __restrict__ yb, float* __restrict__ ybias,
    float* __restrict__ bias32, const _Float16* __restrict__ x0h,
    float* __restrict__ Y) {
  __shared__ float gb[2048];
  const int bid = blockIdx.x;
  const int tid = threadIdx.x;
  if (bid < 32) {  // G[k] = (Bm A^k) @ W2T, packed K=32
    if (tid < 256) {
      const int w = tid >> 6, ln = tid & 15, g = (tid >> 4) & 3;
      const int mt = w & 1, cb = (w >> 1) * 2;
      const _Float16* src = R_rm + (size_t)bid * 24576;
      f4 acc[2];
#pragma unroll
      for (int c = 0; c < 2; c++) { f4 z = {0.f, 0.f, 0.f, 0.f}; acc[c] = z; }
      for (int k0 = 0; k0 < 512; k0 += 32) {
        h8 af = *(const h8*)(src + (size_t)(mt * 16 + ln) * 512 + k0 + g * 8);
#pragma unroll
        for (int c = 0; c < 2; c++) {
          h8 bf = *(const h8*)(SWpk0 + PK512(cb + c, (k0 >> 3) + g, ln));
          acc[c] = MFMA16(af, bf, acc[c]);
        }
      }
      const int r0 = mt * 16 + g * 4;
#pragma unroll
      for (int c = 0; c < 2; c++) {
        _Float16* pd = Gpk + (size_t)bid * 2048 + ((size_t)((cb + c) * 4 + (r0 >> 3)) * 16 + ln) * 8 + (r0 & 7);
#pragma unroll
        for (int r = 0; r < 4; r++) pd[r] = (_Float16)acc[c][r];
      }
    }
  } else if (bid == 32) {  // ybias[t], bias32
    for (int idx = tid; idx < 2048; idx += 512) {
      int i = idx >> 6, c = idx & 63;
      const _Float16* br = R_rm + (size_t)i * 24576 + 32 * 512;
      const float* wc = yw + c * 512;
      float s = 0.f;
#pragma unroll 8
      for (int h = 0; h < 512; h++) s += (float)br[h] * wc[h];
      gb[idx] = s;
    }
    __syncthreads();
    for (int idx = tid; idx < 2048; idx += 512) {
      int t = (idx >> 6) + 1, c = idx & 63;
      float s = yb[c];
      for (int i = 0; i < t; i++) s += gb[i * 64 + c];
      ybias[t * 64 + c] = s;
    }
    for (int n = tid; n < 512; n += 512) {
      float s = 0.f;
#pragma unroll
      for (int i = 0; i < 32; i++) s += (float)R_rm[(size_t)i * 24576 + 32 * 512 + n];
      bias32[n] = s;
    }
  } else {  // Y[0] = x0 @ W2T + yb
    const int w = tid >> 6, ln = tid & 15, g = (tid >> 4) & 3;
    f4 acc[4];
#pragma unroll
    for (int c = 0; c < 4; c++) { f4 z = {0.f, 0.f, 0.f, 0.f}; acc[c] = z; }
    for (int k0 = 0; k0 < 512; k0 += 32) {
      h8 af = *(const h8*)(x0h + (size_t)(w * 16 + ln) * 512 + k0 + g * 8);
#pragma unroll
      for (int c = 0; c < 4; c++) {
        h8 bf = *(const h8*)(SWpk0 + PK512(c, (k0 >> 3) + g, ln));
        acc[c] = MFMA16(af, bf, acc[c]);
      }
    }
#pragma unroll
    for (int c = 0; c < 4; c++) {
      int col = c * 16 + ln;
#pragma unroll
      for (int r = 0; r < 4; r++)
        Y[(size_t)(w * 16 + g * 4 + r) * 64 + col] = acc[c][r] + yb[col];
    }
  }
}

// ---------------- pass 1: r_j = Ublk_j @ Wst + bias32 (+ x0 A^32 for j=0) ----------------
__global__ __launch_bounds__(512) void k_p1(
    const float* __restrict__ U, const _Float16* __restrict__ Wst_pk,
    const _Float16* __restrict__ x0h, const _Float16* __restrict__ A32_pk,
    const float* __restrict__ bias32, _Float16* __restrict__ Zh) {
  const int rb = blockIdx.x, j = blockIdx.y;
  const int row0 = rb * 32;
  const int tid = threadIdx.x;
  const int w = tid >> 6, ln = tid & 15, g = (tid >> 4) & 3;
  f4 acc[2][4];
#pragma unroll
  for (int tm = 0; tm < 2; tm++)
#pragma unroll
    for (int i = 0; i < 4; i++) { f4 z = {0.f, 0.f, 0.f, 0.f}; acc[tm][i] = z; }
#pragma unroll 4
  for (int t = 0; t < 32; t++) {
    const _Float16* wp = Wst_pk + (size_t)(31 - t) * 16384;
    h8 uf[2];
#pragma unroll
    for (int tm = 0; tm < 2; tm++) {
      const float* up = U + ((size_t)(j * 32 + t) * 128 + row0 + tm * 16 + ln) * 32 + g * 8;
      const float4 ua = *(const float4*)up;
      const float4 ub = *(const float4*)(up + 4);
      h8 v;
      v[0] = (_Float16)ua.x; v[1] = (_Float16)ua.y; v[2] = (_Float16)ua.z; v[3] = (_Float16)ua.w;
      v[4] = (_Float16)ub.x; v[5] = (_Float16)ub.y; v[6] = (_Float16)ub.z; v[7] = (_Float16)ub.w;
      uf[tm] = v;
    }
#pragma unroll
    for (int i = 0; i < 4; i++) {
      h8 bf = *(const h8*)(wp + ((size_t)((w * 4 + i) * 4 + g) * 16 + ln) * 8);
#pragma unroll
      for (int tm = 0; tm < 2; tm++) acc[tm][i] = MFMA16(uf[tm], bf, acc[tm][i]);
    }
  }
  if (j == 0) {
    for (int k0 = 0; k0 < 512; k0 += 32) {
      h8 af[2];
#pragma unroll
      for (int tm = 0; tm < 2; tm++)
        af[tm] = *(const h8*)(x0h + (size_t)(row0 + tm * 16 + ln) * 512 + k0 + g * 8);
#pragma unroll
      for (int i = 0; i < 4; i++) {
        h8 bf = *(const h8*)(A32_pk + PK512(w * 4 + i, (k0 >> 3) + g, ln));
#pragma unroll
        for (int tm = 0; tm < 2; tm++) acc[tm][i] = MFMA16(af[tm], bf, acc[tm][i]);
      }
    }
  }
#pragma unroll
  for (int tm = 0; tm < 2; tm++)
#pragma unroll
    for (int i = 0; i < 4; i++) {
      const int n = (w * 4 + i) * 16 + ln;
      const float bz = bias32[n];
#pragma unroll
      for (int r = 0; r < 4; r++) {
        const int mr = tm * 16 + g * 4 + r;
        Zh[((size_t)j * 128 + row0 + mr) * 512 + n] = (_Float16)(acc[tm][i][r] + bz);
      }
    }
}

// ---------------- scan sweep: Zout[j] = Zin[j-d] @ A^{32d} + Zin[j] ----------------
__global__ __launch_bounds__(512) void k_scan(
    const _Float16* __restrict__ Zin, _Float16* __restrict__ Zout,
    const _Float16* __restrict__ P_pk, int d) {
  extern __shared__ char smem[];  // 16 KB
  const int rb = blockIdx.x, j = blockIdx.y;
  const int row0 = rb * 16;
  const int tid = threadIdx.x;
  if (j < d) {
    const uint4* s = (const uint4*)(Zin + ((size_t)j * 128 + row0) * 512);
    uint4* dst = (uint4*)(Zout + ((size_t)j * 128 + row0) * 512);
#pragma unroll
    for (int q = 0; q < 2; q++) dst[tid + q * 512] = s[tid + q * 512];
    return;
  }
  const int w = tid >> 6, ln = tid & 15, g = (tid >> 4) & 3;
  {
    const int row = tid >> 5;
    const int c = (tid & 31) * 16;
    const _Float16* s = Zin + ((size_t)(j - d) * 128 + row0 + row) * 512 + c;
#pragma unroll
    for (int q = 0; q < 2; q++)
      *(h8*)(smem + xoff(row, 2 * (c + q * 8))) = *(const h8*)(s + q * 8);
  }
  __syncthreads();
  f4 acc[4];
#pragma unroll
  for (int i = 0; i < 4; i++) {
    const int n = (w * 4 + i) * 16 + ln;
#pragma unroll
    for (int r = 0; r < 4; r++)
      acc[i][r] = (float)Zin[((size_t)j * 128 + row0 + g * 4 + r) * 512 + n];
  }
#pragma unroll 4
  for (int k0 = 0; k0 < 512; k0 += 32) {
    h8 xa = *(const h8*)(smem + xoff(ln, 2 * k0 + 16 * g));
#pragma unroll
    for (int i = 0; i < 4; i++) {
      h8 bf = *(const h8*)(P_pk + PK512(w * 4 + i, (k0 >> 3) + g, ln));
      acc[i] = MFMA16(xa, bf, acc[i]);
    }
  }
#pragma unroll
  for (int i = 0; i < 4; i++) {
    const int n = (w * 4 + i) * 16 + ln;
#pragma unroll
    for (int r = 0; r < 4; r++)
      Zout[((size_t)j * 128 + row0 + g * 4 + r) * 512 + n] = (_Float16)acc[i][r];
  }
}

// ---------------- pass 2: t-paired, XCD-grouped, balanced ----------------
// 1024 blocks: chunk j = (b&7)*8 + ((b>>3)>>4) (all 16 t-pair blocks of a chunk
// share one XCD's L2); pair (ta, tb=33-ta): per-block K-work = 2080 constant.
// Wave w owns m-tile w (rows w*16..+15), computes BOTH t-halves (A-frag shared).
__global__ __launch_bounds__(512) void k_p2(
    const float* __restrict__ U, const _Float16* __restrict__ Zh,
    const _Float16* __restrict__ x0h, const _Float16* __restrict__ SWpk,
    const _Float16* __restrict__ Gpk, const float* __restrict__ ybias,
    float* __restrict__ Y) {
  const int b = blockIdx.x;
  const int r = b >> 3;
  const int j = (b & 7) * 8 + (r >> 4);
  const int ta = (r & 15) + 1, tb = 33 - ta;
  const int tid = threadIdx.x;
  const int w = tid >> 6, ln = tid & 15, g = (tid >> 4) & 3;
  const int row = w * 16 + ln;
  const _Float16* S = (j == 0) ? x0h : (Zh + (size_t)(j - 1) * 65536);
  const _Float16* SWa = SWpk + (size_t)ta * 32768;
  const _Float16* SWb = SWpk + (size_t)tb * 32768;
  f4 acc[2][4];
#pragma unroll
  for (int th = 0; th < 2; th++)
#pragma unroll
    for (int c = 0; c < 4; c++) { f4 z = {0.f, 0.f, 0.f, 0.f}; acc[th][c] = z; }
  // s-part: K=512, A-frag shared by both halves
#pragma unroll 4
  for (int k0 = 0; k0 < 512; k0 += 32) {
    h8 af = *(const h8*)(S + (size_t)row * 512 + k0 + g * 8);
#pragma unroll
    for (int c = 0; c < 4; c++) {
      h8 b0 = *(const h8*)(SWa + PK512(c, (k0 >> 3) + g, ln));
      acc[0][c] = MFMA16(af, b0, acc[0][c]);
      h8 b1 = *(const h8*)(SWb + PK512(c, (k0 >> 3) + g, ln));
      acc[1][c] = MFMA16(af, b1, acc[1][c]);
    }
  }
  // u-part: i<ta feeds both halves; ta<=i<tb feeds tb only
  const size_t ubase = ((size_t)(j * 32) * 128 + row) * 32 + g * 8;
#pragma unroll 2
  for (int i = 0; i < ta; ++i) {
    const float* up = U + ubase + (size_t)i * 4096;
    const float4 ua = *(const float4*)up;
    const float4 ub = *(const float4*)(up + 4);
    h8 af;
    af[0] = (_Float16)ua.x; af[1] = (_Float16)ua.y; af[2] = (_Float16)ua.z; af[3] = (_Float16)ua.w;
    af[4] = (_Float16)ub.x; af[5] = (_Float16)ub.y; af[6] = (_Float16)ub.z; af[7] = (_Float16)ub.w;
    const _Float16* ga = Gpk + (size_t)(ta - 1 - i) * 2048;
    const _Float16* gbp = Gpk + (size_t)(tb - 1 - i) * 2048;
#pragma unroll
    for (int c = 0; c < 4; c++) {
      acc[0][c] = MFMA16(af, *(const h8*)(ga + ((size_t)(c * 4 + g) * 16 + ln) * 8), acc[0][c]);
      acc[1][c] = MFMA16(af, *(const h8*)(gbp + ((size_t)(c * 4 + g) * 16 + ln) * 8), acc[1][c]);
    }
  }
#pragma unroll 2
  for (int i = ta; i < tb; ++i) {
    const float* up = U + ubase + (size_t)i * 4096;
    const float4 ua = *(const float4*)up;
    const float4 ub = *(const float4*)(up + 4);
    h8 af;
    af[0] = (_Float16)ua.x; af[1] = (_Float16)ua.y; af[2] = (_Float16)ua.z; af[3] = (_Float16)ua.w;
    af[4] = (_Float16)ub.x; af[5] = (_Float16)ub.y; af[6] = (_Float16)ub.z; af[7] = (_Float16)ub.w;
    const _Float16* gbp = Gpk + (size_t)(tb - 1 - i) * 2048;
#pragma unroll
    for (int c = 0; c < 4; c++)
      acc[1][c] = MFMA16(af, *(const h8*)(gbp + ((size_t)(c * 4 + g) * 16 + ln) * 8), acc[1][c]);
  }
  // epilogue
#pragma unroll
  for (int th = 0; th < 2; th++) {
    const int tw = th ? tb : ta;
    const size_t ybase = (size_t)(j * 32 + tw) * 128;
#pragma unroll
    for (int c = 0; c < 4; c++) {
      const int col = c * 16 + ln;
      const float yv = ybias[tw * 64 + col];
#pragma unroll
      for (int rr = 0; rr < 4; rr++)
        Y[(ybase + w * 16 + g * 4 + rr) * 64 + col] = acc[th][c][rr] + yv;
    }
  }
}

extern "C" void kernel_launch(void* const* d_in, const int* in_sizes, int n_in,
                              void* d_out, int out_size, void* d_ws, size_t ws_size,
                              hipStream_t stream) {
  const float* y0   = (const float*)d_in[0];
  const float* U    = (const float*)d_in[1];
  const float* y2xw = (const float*)d_in[2];
  const float* y2xb = (const float*)d_in[3];
  const float* xw   = (const float*)d_in[4];
  const float* xub  = (const float*)d_in[5];
  const float* x2yw = (const float*)d_in[6];
  const float* x2yb = (const float*)d_in[7];
  float* Y = (float*)d_out;
  char* ws = (char*)d_ws;

  _Float16* A_rm  = (_Float16*)(ws + 0x000000);
  _Float16* A_pk  = (_Float16*)(ws + 0x080000);
  auto rm = [&](int m) { return (_Float16*)(ws + 0x100000 + (size_t)(m - 1) * 0x80000); }; // m=1..7
  auto pkL = [&](int m) { return (_Float16*)(ws + 0x480000 + (size_t)(m - 1) * 0x80000); }; // m=1..4
  _Float16* R_rm  = (_Float16*)(ws + 0x680000);   // 32 x [48x512]
  _Float16* Z2    = (_Float16*)(ws + 0x000000);   // scan ping buffer (aliases dead chain bufs)
  _Float16* Zh    = (_Float16*)(ws + 0x800000);   // 8 MB
  auto pkH = [&](int m) { return (_Float16*)(ws + 0x1000000 + (size_t)(m - 5) * 0x80000); }; // m=5..8
  _Float16* Wst_pk = (_Float16*)(ws + 0x1200000); // 1 MB
  _Float16* SWpk   = (_Float16*)(ws + 0x1300000); // 33 x 64KB
  _Float16* Gpk    = (_Float16*)(ws + 0x1510000); // 64 KB
  float*    ybias  = (float*)   (ws + 0x1530000);
  float*    bias32 = (float*)   (ws + 0x1534000);
  _Float16* x0h    = (_Float16*)(ws + 0x1538000); // 128 KB -> 22.3 MB total
  auto pw_rm = [&](int m) { return m == 0 ? A_rm : rm(m); };
  auto pw_pk = [&](int m) { return m == 0 ? A_pk : (m <= 4 ? pkL(m) : pkH(m)); };

  k_prep0<<<548, 256, 0, stream>>>(xw, x2yw, xub, y0, y2xw, y2xb,
                                   A_pk, A_rm, SWpk, R_rm, Wst_pk, x0h);
  for (int m = 0; m < 8; m++) {
    int nR = (m <= 4) ? (1 << m) : 0;
    int nSW = (m <= 4) ? (1 << m) : (m == 5 ? 1 : 0);
    int off = (m == 5) ? 32 : (1 << m);
    _Float16* rmo = (m == 7) ? rm(1) : rm(m + 1);
    k_chain<<<256 + nR + 8 * nSW, 256, 0, stream>>>(
        pw_rm(m), pw_pk(m), rmo, pw_pk(m + 1), R_rm, Wst_pk, SWpk, nR, nSW, off);
  }
  k_aux<<<34, 512, 0, stream>>>(R_rm, SWpk, Gpk, x2yw, x2yb, ybias, bias32, x0h, Y);
  k_p1<<<dim3(4, T_CH), 512, 0, stream>>>(U, Wst_pk, x0h, pkH(5), bias32, Zh);
  k_scan<<<dim3(8, T_CH), 512, 16384, stream>>>(Zh, Z2, pkH(5), 1);
  k_scan<<<dim3(8, T_CH), 512, 16384, stream>>>(Z2, Zh, pkH(6), 2);
  k_scan<<<dim3(8, T_CH), 512, 16384, stream>>>(Zh, Z2, pkH(7), 4);
  k_scan<<<dim3(8, T_CH), 512, 16384, stream>>>(Z2, Zh, pkH(8), 8);
  k_p2<<<1024, 512, 0, stream>>>(U, Zh, x0h, SWpk, Gpk, ybias, Y);
}

// Round 8
// 570.517 us; speedup vs baseline: 1.9991x; 1.0664x over previous
//
#include <hip/hip_runtime.h>

// Linear RNN via tap-GEMM decomposition on MI355X (gfx950).
// x_{k+1} = x_k A + u_k Bm + b ;  Y_t = x_t W2^T + yb
// NY=64 NU=32 NH=512 NHRZ=2048 B=128.  64 chunks of 32 steps.
//
// r_j = sum_t u_{32j+t} (Bm A^{31-t}) + bias32 (+ x0 A^32, j=0)   [k_p1]
// Z   = windowed Kogge-Stone prefix (window 16)                   [k_scan x4]
// Y[32j+t] = s_j (A^t W2T) + sum_{i<t} u_i G[t-1-i] + ybias[t]    [k_p2 v3]
// k_p2 v3: wave=(t-half, col-tile) -> B-frags read ONCE per block; S staged in
// swizzled LDS; U taps phase-staged. Blocks of a chunk share one XCD's L2.
// (Round-8 bisection: round-4 launch structure + k_p2 v3 only.)

#define T_CH 64

typedef _Float16 h8 __attribute__((ext_vector_type(8)));
typedef float    f4 __attribute__((ext_vector_type(4)));

__device__ __forceinline__ f4 MFMA16(h8 a, h8 b, f4 c) {
  return __builtin_amdgcn_mfma_f32_16x16x32_f16(a, b, c, 0, 0, 0);
}
__device__ __forceinline__ int xoff(int row, int bc) {  // swizzled LDS row stride 1024B
  return row * 1024 + (bc ^ ((row & 7) << 4));
}
__device__ __forceinline__ size_t PK512(int tn, int kb, int ln) {
  return ((size_t)(tn * 64 + kb) * 16 + ln) * 8;
}

// ---------------- prep: pack A (pk+rm), W2T->SWpk[0], R0=[Bm;b], Wst_pk[0], x0h ----------------
__global__ __launch_bounds__(256) void k_prep0(
    const float* __restrict__ xw, const float* __restrict__ yw,
    const float* __restrict__ xub, const float* __restrict__ y0,
    const float* __restrict__ y2xw, const float* __restrict__ y2xb,
    _Float16* __restrict__ A_pk, _Float16* __restrict__ A_rm,
    _Float16* __restrict__ SWpk, _Float16* __restrict__ R_rm,
    _Float16* __restrict__ Wst_pk, _Float16* __restrict__ x0h) {
  int tid = blockIdx.x * 256 + threadIdx.x;
  if (tid < 32768) {  // A_pk
    int g = tid; int ln = g & 15, kb = (g >> 4) & 63, tn = g >> 10;
    const float* s = xw + (tn * 16 + ln) * 544 + kb * 8;
    _Float16* d = A_pk + (size_t)g * 8;
#pragma unroll
    for (int j = 0; j < 8; j++) d[j] = (_Float16)s[j];
  } else if (tid < 65536) {  // A_rm
    int g = tid - 32768; int k = g >> 6, n8 = (g & 63) * 8;
#pragma unroll
    for (int j = 0; j < 8; j++) A_rm[(size_t)k * 512 + n8 + j] = (_Float16)xw[(size_t)(n8 + j) * 544 + k];
  } else if (tid < 69632) {  // SWpk[0] = W2T packed
    int g = tid - 65536; int ln = g & 15, kb = (g >> 4) & 63, tn = g >> 10;
    const float* s = yw + (tn * 16 + ln) * 512 + kb * 8;
    _Float16* d = SWpk + (size_t)g * 8;
#pragma unroll
    for (int j = 0; j < 8; j++) d[j] = (_Float16)s[j];
  } else if (tid < 72704) {  // R_rm[0] = [Bm(32); b(1); 0(15)]
    int g = tid - 69632; int row = g >> 6, n8 = (g & 63) * 8;
#pragma unroll
    for (int j = 0; j < 8; j++) {
      float v = 0.f;
      if (row < 32) v = xw[(size_t)(n8 + j) * 544 + 512 + row];
      else if (row == 32) v = xub[n8 + j];
      R_rm[(size_t)row * 512 + n8 + j] = (_Float16)v;
    }
  } else if (tid < 74752) {  // Wst_pk[0] = packed Bm (K=32)
    int g = tid - 72704; int ln = g & 15, gg = (g >> 4) & 3, tn = g >> 6;
    _Float16* d = Wst_pk + (size_t)g * 8;
#pragma unroll
    for (int j = 0; j < 8; j++) d[j] = (_Float16)xw[(size_t)(tn * 16 + ln) * 544 + 512 + gg * 8 + j];
  } else if (tid < 140288) {  // x0h = f16(y0 @ y2x_w^T + y2x_b)
    int id = tid - 74752;
    int bb = id >> 9, h = id & 511;
    float acc = y2xb[h];
    const float* wr = y2xw + h * 64;
    const float* yr = y0 + bb * 64;
#pragma unroll 8
    for (int i = 0; i < 64; i++) acc += yr[i] * wr[i];
    x0h[(size_t)bb * 512 + h] = (_Float16)acc;
  }
}

// ---------------- fused chain level: sq (A^{2^{m+1}}) | R-taps | SW-taps ----------------
__global__ __launch_bounds__(256) void k_chain(
    const _Float16* __restrict__ rm_in, const _Float16* __restrict__ pk_in,
    _Float16* __restrict__ rm_out, _Float16* __restrict__ pk_out,
    _Float16* __restrict__ R_rm, _Float16* __restrict__ Wst_pk,
    _Float16* __restrict__ SWpk, int nR, int nSW, int off) {
  const int bid = blockIdx.x;
  const int tid = threadIdx.x;
  const int w = tid >> 6, ln = tid & 15, g = (tid >> 4) & 3;
  if (bid < 256) {  // ---- squaring GEMM, 32x32 tile ----
    const int Mb = (bid >> 4) * 32, Nb = (bid & 15) * 32;
    const int mt = w >> 1, nt = w & 1;
    const int mrow = Mb + mt * 16 + ln;
    f4 acc = {0.f, 0.f, 0.f, 0.f};
    for (int k0 = 0; k0 < 512; k0 += 32) {
      h8 af = *(const h8*)(rm_in + (size_t)mrow * 512 + k0 + g * 8);
      h8 bf = *(const h8*)(pk_in + PK512((Nb >> 4) + nt, (k0 >> 3) + g, ln));
      acc = MFMA16(af, bf, acc);
    }
    const int mr0 = Mb + mt * 16 + g * 4;
    const int n = Nb + nt * 16 + ln;
#pragma unroll
    for (int r = 0; r < 4; r++) rm_out[(size_t)(mr0 + r) * 512 + n] = (_Float16)acc[r];
    _Float16* pd = pk_out + (size_t)((n >> 4) * 64 + (mr0 >> 3)) * 128 + (n & 15) * 8 + (mr0 & 7);
#pragma unroll
    for (int r = 0; r < 4; r++) pd[r] = (_Float16)acc[r];
  } else if (bid < 256 + nR) {  // ---- R chain: [48x512] = R[k] @ pw ----
    const int k = bid - 256;
    const _Float16* src = R_rm + (size_t)k * 24576;
    _Float16* dst = R_rm + (size_t)(k + off) * 24576;
    _Float16* wpk = Wst_pk + (size_t)(k + off) * 16384;
    f4 acc[3][8];
#pragma unroll
    for (int mt = 0; mt < 3; mt++)
#pragma unroll
      for (int i = 0; i < 8; i++) { f4 z = {0.f, 0.f, 0.f, 0.f}; acc[mt][i] = z; }
    for (int k0 = 0; k0 < 512; k0 += 32) {
      h8 af[3];
#pragma unroll
      for (int mt = 0; mt < 3; mt++)
        af[mt] = *(const h8*)(src + (size_t)(mt * 16 + ln) * 512 + k0 + g * 8);
#pragma unroll
      for (int i = 0; i < 8; i++) {
        h8 bf = *(const h8*)(pk_in + PK512(w * 8 + i, (k0 >> 3) + g, ln));
#pragma unroll
        for (int mt = 0; mt < 3; mt++) acc[mt][i] = MFMA16(af[mt], bf, acc[mt][i]);
      }
    }
#pragma unroll
    for (int mt = 0; mt < 3; mt++)
#pragma unroll
      for (int i = 0; i < 8; i++) {
        int tn = w * 8 + i, col = tn * 16 + ln;
        int r0 = mt * 16 + g * 4;
#pragma unroll
        for (int r = 0; r < 4; r++) dst[(size_t)(r0 + r) * 512 + col] = (_Float16)acc[mt][i][r];
        if (mt < 2) {
          _Float16* pd = wpk + ((size_t)(tn * 4 + (r0 >> 3)) * 16 + ln) * 8 + (r0 & 7);
#pragma unroll
          for (int r = 0; r < 4; r++) pd[r] = (_Float16)acc[mt][i][r];
        }
      }
  } else {  // ---- SW chain: SW[t+off] = pw_rm @ SW[t] ----
    const int q = bid - 256 - nR;
    const int t = q >> 3, mb = q & 7;
    const _Float16* src = SWpk + (size_t)t * 32768;
    _Float16* dst = SWpk + (size_t)(t + off) * 32768;
    f4 acc[4];
#pragma unroll
    for (int c = 0; c < 4; c++) { f4 z = {0.f, 0.f, 0.f, 0.f}; acc[c] = z; }
    const int rbase = mb * 64 + w * 16;
    for (int k0 = 0; k0 < 512; k0 += 32) {
      h8 af = *(const h8*)(rm_in + (size_t)(rbase + ln) * 512 + k0 + g * 8);
#pragma unroll
      for (int c = 0; c < 4; c++) {
        h8 bf = *(const h8*)(src + PK512(c, (k0 >> 3) + g, ln));
        acc[c] = MFMA16(af, bf, acc[c]);
      }
    }
    const int r0 = rbase + g * 4;
#pragma unroll
    for (int c = 0; c < 4; c++) {
      _Float16* pd = dst + ((size_t)(c * 64 + (r0 >> 3)) * 16 + ln) * 8 + (r0 & 7);
#pragma unroll
      for (int r = 0; r < 4; r++) pd[r] = (_Float16)acc[c][r];
    }
  }
}

// ---------------- aux: Gpk taps (blocks 0..31) | ybias+bias32 (32) | Y[0] (33) ----------------
__global__ __launch_bounds__(512) void k_aux(
    const _Float16* __restrict__ R_rm, const _Float16* __restrict__ SWpk0,
    _Float16* __restrict__ Gpk, const float* __restrict__ yw,
    const float* __restrict__ yb, float* __restrict__ ybias,
    float* __restrict__ bias32, const _Float16* __restrict__ x0h,
    float* __restrict__ Y) {
  __shared__ float gb[2048];
  const int bid = blockIdx.x;
  const int tid = threadIdx.x;
  if (bid < 32) {  // G[k] = (Bm A^k) @ W2T, packed K=32
    if (tid < 256) {
      const int w = tid >> 6, ln = tid & 15, g = (tid >> 4) & 3;
      const int mt = w & 1, cb = (w >> 1) * 2;
      const _Float16* src = R_rm + (size_t)bid * 24576;
      f4 acc[2];
#pragma unroll
      for (int c = 0; c < 2; c++) { f4 z = {0.f, 0.f, 0.f, 0.f}; acc[c] = z; }
      for (int k0 = 0; k0 < 512; k0 += 32) {
        h8 af = *(const h8*)(src + (size_t)(mt * 16 + ln) * 512 + k0 + g * 8);
#pragma unroll
        for (int c = 0; c < 2; c++) {
          h8 bf = *(const h8*)(SWpk0 + PK512(cb + c, (k0 >> 3) + g, ln));
          acc[c] = MFMA16(af, bf, acc[c]);
        }
      }
      const int r0 = mt * 16 + g * 4;
#pragma unroll
      for (int c = 0; c < 2; c++) {
        _Float16* pd = Gpk + (size_t)bid * 2048 + ((size_t)((cb + c) * 4 + (r0 >> 3)) * 16 + ln) * 8 + (r0 & 7);
#pragma unroll
        for (int r = 0; r < 4; r++) pd[r] = (_Float16)acc[c][r];
      }
    }
  } else if (bid == 32) {  // ybias[t], bias32
    for (int idx = tid; idx < 2048; idx += 512) {
      int i = idx >> 6, c = idx & 63;
      const _Float16* br = R_rm + (size_t)i * 24576 + 32 * 512;
      const float* wc = yw + c * 512;
      float s = 0.f;
#pragma unroll 8
      for (int h = 0; h < 512; h++) s += (float)br[h] * wc[h];
      gb[idx] = s;
    }
    __syncthreads();
    for (int idx = tid; idx < 2048; idx += 512) {
      int t = (idx >> 6) + 1, c = idx & 63;
      float s = yb[c];
      for (int i = 0; i < t; i++) s += gb[i * 64 + c];
      ybias[t * 64 + c] = s;
    }
    for (int n = tid; n < 512; n += 512) {
      float s = 0.f;
#pragma unroll
      for (int i = 0; i < 32; i++) s += (float)R_rm[(size_t)i * 24576 + 32 * 512 + n];
      bias32[n] = s;
    }
  } else {  // Y[0] = x0 @ W2T + yb
    const int w = tid >> 6, ln = tid & 15, g = (tid >> 4) & 3;
    f4 acc[4];
#pragma unroll
    for (int c = 0; c < 4; c++) { f4 z = {0.f, 0.f, 0.f, 0.f}; acc[c] = z; }
    for (int k0 = 0; k0 < 512; k0 += 32) {
      h8 af = *(const h8*)(x0h + (size_t)(w * 16 + ln) * 512 + k0 + g * 8);
#pragma unroll
      for (int c = 0; c < 4; c++) {
        h8 bf = *(const h8*)(SWpk0 + PK512(c, (k0 >> 3) + g, ln));
        acc[c] = MFMA16(af, bf, acc[c]);
      }
    }
#pragma unroll
    for (int c = 0; c < 4; c++) {
      int col = c * 16 + ln;
#pragma unroll
      for (int r = 0; r < 4; r++)
        Y[(size_t)(w * 16 + g * 4 + r) * 64 + col] = acc[c][r] + yb[col];
    }
  }
}

// ---------------- pass 1: r_j = Ublk_j @ Wst + bias32 (+ x0 A^32 for j=0) ----------------
__global__ __launch_bounds__(512) void k_p1(
    const float* __restrict__ U, const _Float16* __restrict__ Wst_pk,
    const _Float16* __restrict__ x0h, const _Float16* __restrict__ A32_pk,
    const float* __restrict__ bias32, _Float16* __restrict__ Zh) {
  const int rb = blockIdx.x, j = blockIdx.y;
  const int row0 = rb * 32;
  const int tid = threadIdx.x;
  const int w = tid >> 6, ln = tid & 15, g = (tid >> 4) & 3;
  f4 acc[2][4];
#pragma unroll
  for (int tm = 0; tm < 2; tm++)
#pragma unroll
    for (int i = 0; i < 4; i++) { f4 z = {0.f, 0.f, 0.f, 0.f}; acc[tm][i] = z; }
#pragma unroll 4
  for (int t = 0; t < 32; t++) {
    const _Float16* wp = Wst_pk + (size_t)(31 - t) * 16384;
    h8 uf[2];
#pragma unroll
    for (int tm = 0; tm < 2; tm++) {
      const float* up = U + ((size_t)(j * 32 + t) * 128 + row0 + tm * 16 + ln) * 32 + g * 8;
      const float4 ua = *(const float4*)up;
      const float4 ub = *(const float4*)(up + 4);
      h8 v;
      v[0] = (_Float16)ua.x; v[1] = (_Float16)ua.y; v[2] = (_Float16)ua.z; v[3] = (_Float16)ua.w;
      v[4] = (_Float16)ub.x; v[5] = (_Float16)ub.y; v[6] = (_Float16)ub.z; v[7] = (_Float16)ub.w;
      uf[tm] = v;
    }
#pragma unroll
    for (int i = 0; i < 4; i++) {
      h8 bf = *(const h8*)(wp + ((size_t)((w * 4 + i) * 4 + g) * 16 + ln) * 8);
#pragma unroll
      for (int tm = 0; tm < 2; tm++) acc[tm][i] = MFMA16(uf[tm], bf, acc[tm][i]);
    }
  }
  if (j == 0) {
    for (int k0 = 0; k0 < 512; k0 += 32) {
      h8 af[2];
#pragma unroll
      for (int tm = 0; tm < 2; tm++)
        af[tm] = *(const h8*)(x0h + (size_t)(row0 + tm * 16 + ln) * 512 + k0 + g * 8);
#pragma unroll
      for (int i = 0; i < 4; i++) {
        h8 bf = *(const h8*)(A32_pk + PK512(w * 4 + i, (k0 >> 3) + g, ln));
#pragma unroll
        for (int tm = 0; tm < 2; tm++) acc[tm][i] = MFMA16(af[tm], bf, acc[tm][i]);
      }
    }
  }
#pragma unroll
  for (int tm = 0; tm < 2; tm++)
#pragma unroll
    for (int i = 0; i < 4; i++) {
      const int n = (w * 4 + i) * 16 + ln;
      const float bz = bias32[n];
#pragma unroll
      for (int r = 0; r < 4; r++) {
        const int mr = tm * 16 + g * 4 + r;
        Zh[((size_t)j * 128 + row0 + mr) * 512 + n] = (_Float16)(acc[tm][i][r] + bz);
      }
    }
}

// ---------------- scan sweep: Zout[j] = Zin[j-d] @ A^{32d} + Zin[j] ----------------
__global__ __launch_bounds__(512) void k_scan(
    const _Float16* __restrict__ Zin, _Float16* __restrict__ Zout,
    const _Float16* __restrict__ P_pk, int d) {
  extern __shared__ char smem[];  // 16 KB
  const int rb = blockIdx.x, j = blockIdx.y;
  const int row0 = rb * 16;
  const int tid = threadIdx.x;
  if (j < d) {
    const uint4* s = (const uint4*)(Zin + ((size_t)j * 128 + row0) * 512);
    uint4* dst = (uint4*)(Zout + ((size_t)j * 128 + row0) * 512);
#pragma unroll
    for (int q = 0; q < 2; q++) dst[tid + q * 512] = s[tid + q * 512];
    return;
  }
  const int w = tid >> 6, ln = tid & 15, g = (tid >> 4) & 3;
  {
    const int row = tid >> 5;
    const int c = (tid & 31) * 16;
    const _Float16* s = Zin + ((size_t)(j - d) * 128 + row0 + row) * 512 + c;
#pragma unroll
    for (int q = 0; q < 2; q++)
      *(h8*)(smem + xoff(row, 2 * (c + q * 8))) = *(const h8*)(s + q * 8);
  }
  __syncthreads();
  f4 acc[4];
#pragma unroll
  for (int i = 0; i < 4; i++) {
    const int n = (w * 4 + i) * 16 + ln;
#pragma unroll
    for (int r = 0; r < 4; r++)
      acc[i][r] = (float)Zin[((size_t)j * 128 + row0 + g * 4 + r) * 512 + n];
  }
#pragma unroll 4
  for (int k0 = 0; k0 < 512; k0 += 32) {
    h8 xa = *(const h8*)(smem + xoff(ln, 2 * k0 + 16 * g));
#pragma unroll
    for (int i = 0; i < 4; i++) {
      h8 bf = *(const h8*)(P_pk + PK512(w * 4 + i, (k0 >> 3) + g, ln));
      acc[i] = MFMA16(xa, bf, acc[i]);
    }
  }
#pragma unroll
  for (int i = 0; i < 4; i++) {
    const int n = (w * 4 + i) * 16 + ln;
#pragma unroll
    for (int r = 0; r < 4; r++)
      Zout[((size_t)j * 128 + row0 + g * 4 + r) * 512 + n] = (_Float16)acc[i][r];
  }
}

// =================== k_p2 v3: output GEMMs, wave=(t-half,col), LDS-staged ===================
// 2048 blocks = (chunk j, row-half h, pair p); chunk's 32 blocks share one XCD.
__global__ __launch_bounds__(512) void k_p2(
    const float* __restrict__ U, const _Float16* __restrict__ Zh,
    const _Float16* __restrict__ x0h, const _Float16* __restrict__ SWpk,
    const _Float16* __restrict__ Gpk, const float* __restrict__ ybias,
    float* __restrict__ Y) {
  __shared__ char Ssw[65536];   // 64 rows x 1024B, swizzled
  __shared__ char Ufr[16384];   // 4 taps x 4 mt x 64 lanes x 16B (A-frag ready)
  const int b = blockIdx.x, tid = threadIdx.x;
  const int lb = b >> 3;
  const int j = (b & 7) * 8 + (lb >> 5);
  const int q = lb & 31;
  const int h = q >> 4, p = q & 15;
  const int ta = p + 1, tb = 33 - ta;
  const int row0 = h * 64;
  const int w = tid >> 6, ln = tid & 15, g = (tid >> 4) & 3, l = tid & 63;
  const int th = w >> 2, c = w & 3;
  const int t_th = th ? tb : ta;
  const _Float16* S = (j == 0) ? x0h : (Zh + (size_t)(j - 1) * 65536);

  auto stageU = [&](int ph) {
#pragma unroll
    for (int fo = 0; fo < 2; fo++) {
      const int fi = tid + fo * 512;
      const int i4 = fi >> 8, mt = (fi >> 6) & 3, fl = fi & 63;
      const int fln = fl & 15, fg = fl >> 4;
      const float* up = U + ((size_t)(j * 32 + ph * 4 + i4) * 128 + row0 + mt * 16 + fln) * 32 + fg * 8;
      const float4 ua = *(const float4*)up;
      const float4 ub = *(const float4*)(up + 4);
      h8 v;
      v[0] = (_Float16)ua.x; v[1] = (_Float16)ua.y; v[2] = (_Float16)ua.z; v[3] = (_Float16)ua.w;
      v[4] = (_Float16)ub.x; v[5] = (_Float16)ub.y; v[6] = (_Float16)ub.z; v[7] = (_Float16)ub.w;
      *(h8*)(Ufr + (size_t)fi * 16) = v;
    }
  };

  {  // stage S-half (64 rows x 512 f16) swizzled
    const int row = tid >> 3;
    const int c0 = (tid & 7) * 64;
    const _Float16* sp = S + (size_t)(row0 + row) * 512 + c0;
#pragma unroll
    for (int qq = 0; qq < 8; qq++)
      *(h8*)(Ssw + xoff(row, 2 * (c0 + qq * 8))) = *(const h8*)(sp + qq * 8);
  }
  stageU(0);
  __syncthreads();

  f4 acc[4];
#pragma unroll
  for (int mt = 0; mt < 4; mt++) { f4 z = {0.f, 0.f, 0.f, 0.f}; acc[mt] = z; }
  // s-part: K=512; one B-frag feeds 4 MFMAs
  const _Float16* SW = SWpk + (size_t)t_th * 32768;
#pragma unroll 4
  for (int k0 = 0; k0 < 512; k0 += 32) {
    h8 bf = *(const h8*)(SW + PK512(c, (k0 >> 3) + g, ln));
#pragma unroll
    for (int mt = 0; mt < 4; mt++) {
      h8 af = *(const h8*)(Ssw + xoff(mt * 16 + ln, 2 * k0 + 16 * g));
      acc[mt] = MFMA16(af, bf, acc[mt]);
    }
  }
  // u-part: phased taps (4/phase), block-uniform phase count
  const int nph = (tb + 3) >> 2;
  for (int ph = 0; ph < nph; ph++) {
#pragma unroll
    for (int i4 = 0; i4 < 4; i4++) {
      const int i = ph * 4 + i4;
      if (i < t_th) {
        h8 bf = *(const h8*)(Gpk + (size_t)(t_th - 1 - i) * 2048 + ((size_t)(c * 4 + g) * 16 + ln) * 8);
#pragma unroll
        for (int mt = 0; mt < 4; mt++) {
          h8 af = *(const h8*)(Ufr + (size_t)((i4 * 4 + mt) * 64 + l) * 16);
          acc[mt] = MFMA16(af, bf, acc[mt]);
        }
      }
    }
    if (ph + 1 < nph) {
      __syncthreads();
      stageU(ph + 1);
      __syncthreads();
    }
  }
  // epilogue
  const size_t ybase = (size_t)(j * 32 + t_th) * 128;
  const int col = c * 16 + ln;
  const float yv = ybias[t_th * 64 + col];
#pragma unroll
  for (int mt = 0; mt < 4; mt++)
#pragma unroll
    for (int r = 0; r < 4; r++)
      Y[(ybase + row0 + mt * 16 + g * 4 + r) * 64 + col] = acc[mt][r] + yv;
}

extern "C" void kernel_launch(void* const* d_in, const int* in_sizes, int n_in,
                              void* d_out, int out_size, void* d_ws, size_t ws_size,
                              hipStream_t stream) {
  const float* y0   = (const float*)d_in[0];
  const float* U    = (const float*)d_in[1];
  const float* y2xw = (const float*)d_in[2];
  const float* y2xb = (const float*)d_in[3];
  const float* xw   = (const float*)d_in[4];
  const float* xub  = (const float*)d_in[5];
  const float* x2yw = (const float*)d_in[6];
  const float* x2yb = (const float*)d_in[7];
  float* Y = (float*)d_out;
  char* ws = (char*)d_ws;

  _Float16* A_rm  = (_Float16*)(ws + 0x000000);
  _Float16* A_pk  = (_Float16*)(ws + 0x080000);
  auto rm = [&](int m) { return (_Float16*)(ws + 0x100000 + (size_t)(m - 1) * 0x80000); }; // m=1..7
  auto pkL = [&](int m) { return (_Float16*)(ws + 0x480000 + (size_t)(m - 1) * 0x80000); }; // m=1..4
  _Float16* R_rm  = (_Float16*)(ws + 0x680000);   // 32 x [48x512]
  _Float16* Z2    = (_Float16*)(ws + 0x000000);   // scan ping buffer (aliases dead chain bufs)
  _Float16* Zh    = (_Float16*)(ws + 0x800000);   // 8 MB
  auto pkH = [&](int m) { return (_Float16*)(ws + 0x1000000 + (size_t)(m - 5) * 0x80000); }; // m=5..8
  _Float16* Wst_pk = (_Float16*)(ws + 0x1200000); // 1 MB
  _Float16* SWpk   = (_Float16*)(ws + 0x1300000); // 33 x 64KB
  _Float16* Gpk    = (_Float16*)(ws + 0x1510000); // 128 KB
  float*    ybias  = (float*)   (ws + 0x1530000);
  float*    bias32 = (float*)   (ws + 0x1534000);
  _Float16* x0h    = (_Float16*)(ws + 0x1538000); // 128 KB -> 22.3 MB total
  auto pw_rm = [&](int m) { return m == 0 ? A_rm : rm(m); };
  auto pw_pk = [&](int m) { return m == 0 ? A_pk : (m <= 4 ? pkL(m) : pkH(m)); };

  k_prep0<<<548, 256, 0, stream>>>(xw, x2yw, xub, y0, y2xw, y2xb,
                                   A_pk, A_rm, SWpk, R_rm, Wst_pk, x0h);
  for (int m = 0; m < 8; m++) {
    int nR = (m <= 4) ? (1 << m) : 0;
    int nSW = (m <= 4) ? (1 << m) : (m == 5 ? 1 : 0);
    int off = (m == 5) ? 32 : (1 << m);
    _Float16* rmo = (m == 7) ? rm(1) : rm(m + 1);
    k_chain<<<256 + nR + 8 * nSW, 256, 0, stream>>>(
        pw_rm(m), pw_pk(m), rmo, pw_pk(m + 1), R_rm, Wst_pk, SWpk, nR, nSW, off);
  }
  k_aux<<<34, 512, 0, stream>>>(R_rm, SWpk, Gpk, x2yw, x2yb, ybias, bias32, x0h, Y);
  k_p1<<<dim3(4, T_CH), 512, 0, stream>>>(U, Wst_pk, x0h, pkH(5), bias32, Zh);
  k_scan<<<dim3(8, T_CH), 512, 16384, stream>>>(Zh, Z2, pkH(5), 1);
  k_scan<<<dim3(8, T_CH), 512, 16384, stream>>>(Z2, Zh, pkH(6), 2);
  k_scan<<<dim3(8, T_CH), 512, 16384, stream>>>(Zh, Z2, pkH(7), 4);
  k_scan<<<dim3(8, T_CH), 512, 16384, stream>>>(Z2, Zh, pkH(8), 8);
  k_p2<<<2048, 512, 0, stream>>>(U, Zh, x0h, SWpk, Gpk, ybias, Y);
}